// Round 6
// baseline (917.214 us; speedup 1.0000x reference)
//
#include <hip/hip_runtime.h>
#include <hip/hip_fp16.h>

// MoE top-2 SwiGLU, MI355X. Sparse grouped-GEMM, 256-aligned expert segments.
// Both GEMMs: 256x256 tile, 8 waves, 16x16x32 f16 MFMA, proven 0-conflict XOR
// swizzle (pre-swizzled global source), 4 LDS buffers, distance-2 prefetch,
// 4x-unrolled K-loop with COMPILE-TIME buffer indices (addresses loop-invariant),
// one barrier + counted vmcnt per K-step, setprio on MFMA, XCD-aware ordering.
// gemm1: virtual-N=8192 (w1/w3 interleaved 16-col) -> silu*mul -> h fp16. ORD0.
// gemm2: h @ w2^T -> y fp32, ORD1 (A-panel sharing per XCD). combine: gated sum.

#define NTOK 8192
#define D_ 1024
#define F_ 4096
#define E_ 8
#define SLOT_CAP 18432  // 2*8192 + 8*256

using half8 = __attribute__((ext_vector_type(8))) _Float16;
using half4 = __attribute__((ext_vector_type(4))) _Float16;
using f32x4 = __attribute__((ext_vector_type(4))) float;

__device__ __forceinline__ void gload16(const void* g, void* l) {
  __builtin_amdgcn_global_load_lds((const __attribute__((address_space(1))) void*)g,
                                   (__attribute__((address_space(3))) void*)l, 16, 0, 0);
}

// ---------------- fp32 -> fp16 convert ----------------
__global__ __launch_bounds__(256) void cvt_kernel(const float* __restrict__ src,
                                                  _Float16* __restrict__ dst, int n4) {
  int i = blockIdx.x * 256 + threadIdx.x;
  int stride = gridDim.x * 256;
  for (; i < n4; i += stride) {
    float4 v = ((const float4*)src)[i];
    half4 h;
    h.x = (_Float16)v.x; h.y = (_Float16)v.y; h.z = (_Float16)v.z; h.w = (_Float16)v.w;
    ((half4*)dst)[i] = h;
  }
}

// w1,w3 -> interleaved virtual rows w13[e][8192][1024]:
// vrow = ((f>>4)<<5) | (sel<<4) | (f&15); sel 0=w1(gate), 1=w3(up).
__global__ __launch_bounds__(256) void cvt_w13_kernel(const float* __restrict__ w1,
                                                      const float* __restrict__ w3,
                                                      _Float16* __restrict__ w13, int n4) {
  int i = blockIdx.x * 256 + threadIdx.x;
  int stride = gridDim.x * 256;
  for (; i < n4; i += stride) {
    int d4 = i & 255;   // D/4 = 256
    int row = i >> 8;   // e*4096 + f
    int e = row >> 12, f = row & 4095;
    size_t vbase = ((size_t)e << 13) | ((size_t)(f >> 4) << 5) | (size_t)(f & 15);
    float4 v1 = ((const float4*)w1)[i];
    float4 v3 = ((const float4*)w3)[i];
    half4 h1, h3;
    h1.x = (_Float16)v1.x; h1.y = (_Float16)v1.y; h1.z = (_Float16)v1.z; h1.w = (_Float16)v1.w;
    h3.x = (_Float16)v3.x; h3.y = (_Float16)v3.y; h3.z = (_Float16)v3.z; h3.w = (_Float16)v3.w;
    ((half4*)w13)[vbase * 256 + d4] = h1;
    ((half4*)w13)[(vbase + 16) * 256 + d4] = h3;
  }
}

// ---------------- router (+ fused x fp32->fp16) ----------------
__global__ __launch_bounds__(256) void router_kernel(
    const float* __restrict__ x, const float* __restrict__ rw, const float* __restrict__ rbias,
    _Float16* __restrict__ x16, int* __restrict__ tok_e, float* __restrict__ tok_g,
    int* __restrict__ counts) {
  int wv = threadIdx.x >> 6, lane = threadIdx.x & 63;
  int t = blockIdx.x * 4 + wv;
  const float4* xr = (const float4*)(x + (size_t)t * D_);
  float acc[E_];
#pragma unroll
  for (int e = 0; e < E_; ++e) acc[e] = 0.f;
  for (int i = lane; i < D_ / 4; i += 64) {
    float4 xv = xr[i];
    half4 hx;
    hx.x = (_Float16)xv.x; hx.y = (_Float16)xv.y; hx.z = (_Float16)xv.z; hx.w = (_Float16)xv.w;
    ((half4*)(x16 + (size_t)t * D_))[i] = hx;
#pragma unroll
    for (int e = 0; e < E_; ++e) {
      float4 wv4 = ((const float4*)(rw + (size_t)e * D_))[i];
      acc[e] += xv.x * wv4.x + xv.y * wv4.y + xv.z * wv4.z + xv.w * wv4.w;
    }
  }
#pragma unroll
  for (int e = 0; e < E_; ++e) {
#pragma unroll
    for (int off = 32; off > 0; off >>= 1) acc[e] += __shfl_down(acc[e], off);
  }
  if (lane == 0) {
    float p[E_], mx = -1e30f;
#pragma unroll
    for (int e = 0; e < E_; ++e) { p[e] = acc[e] + rbias[e]; mx = fmaxf(mx, p[e]); }
#pragma unroll
    for (int e = 0; e < E_; ++e) p[e] = expf(p[e] - mx);
    int i0 = 0;
#pragma unroll
    for (int e = 1; e < E_; ++e) if (p[e] > p[i0]) i0 = e;
    int i1 = (i0 == 0) ? 1 : 0;
#pragma unroll
    for (int e = 0; e < E_; ++e) if (e != i0 && p[e] > p[i1]) i1 = e;
    float s = p[i0] + p[i1];
    tok_e[t * 2] = i0; tok_e[t * 2 + 1] = i1;
    tok_g[t * 2] = p[i0] / s; tok_g[t * 2 + 1] = p[i1] / s;
    atomicAdd(&counts[i0], 1); atomicAdd(&counts[i1], 1);
  }
}

__global__ void init_kernel(int* slot_token, int* counts, int* cursor) {
  int i = blockIdx.x * 256 + threadIdx.x;
  if (blockIdx.x == 0 && threadIdx.x < E_) { counts[threadIdx.x] = 0; cursor[threadIdx.x] = 0; }
  if (i < SLOT_CAP) slot_token[i] = 0;  // padding -> token 0 (never combined)
}

__global__ void scan_kernel(const int* __restrict__ counts, int* __restrict__ offs) {
  if (threadIdx.x == 0) {
    int o = 0;
    for (int e = 0; e < E_; ++e) { offs[e] = o; o += ((counts[e] + 255) / 256) * 256; }
    offs[E_] = o;
  }
}

__global__ void scatter_kernel(const int* __restrict__ tok_e, const int* __restrict__ offs,
                               int* __restrict__ cursor, int* __restrict__ slot_token,
                               int* __restrict__ slot_of) {
  int i = blockIdx.x * 256 + threadIdx.x;
  if (i >= NTOK * 2) return;
  int e = tok_e[i];
  int pos = offs[e] + atomicAdd(&cursor[e], 1);
  slot_token[pos] = i >> 1;
  slot_of[i] = pos;
}

// ---------------- pipelined grouped GEMM (16x16x32 f16, BM=256, BN=256) ----------------
// 8 waves (2 wr x 4 wc), per-wave 128x64 output. 4 LDS buffers, distance-2 prefetch,
// 4x-unrolled K-loop with compile-time buffer indices.
// MODE 0: gather-A via slot_token, swiglu epilogue -> fp16 h.  MODE 1: direct-A -> fp32.
// ORD 0: rb-fastest per XCD band (share B panel).  ORD 1: nb-fastest (share A panel).
template <int MODE, int ORD, int KD, int NBN, int RPX, int BEROWS>
__global__ __launch_bounds__(512, 2) void moe_gemm_kernel(
    const _Float16* __restrict__ Amat, const _Float16* __restrict__ Bmat,
    const int* __restrict__ slot_token, const int* __restrict__ offs,
    void* __restrict__ outp) {
  constexpr int BM = 256;
  constexpr int MROW = 8;               // 16-row m-frags per wave
  constexpr int AINS = 2;               // A stage instrs (512 thr x 16B = 128 rows each)
  constexpr int S = AINS + 2;           // stage instrs per tile
  constexpr int AH = BM * 32;           // A halves per buffer (8192)
  constexpr int BUFH = (BM + 256) * 32; // 16384 halves = 32 KB
  constexpr int NT = KD / 32;           // K-steps (multiple of 4)
  __shared__ _Float16 lds[4 * BUFH];    // 128 KB

  int id = blockIdx.x;
  int xcd = id & 7, idx = id >> 3;  // grid = 8 * RPX * NBN
  int rb, nb;
  if constexpr (ORD == 0) {
    int band = idx / (8 * NBN);
    int i2 = idx - band * (8 * NBN);
    int rib = (RPX - band * 8) < 8 ? (RPX - band * 8) : 8;
    nb = i2 / rib;
    rb = xcd * RPX + band * 8 + (i2 - nb * rib);
  } else {
    nb = idx % NBN;
    rb = xcd * RPX + idx / NBN;
  }
  int row0 = rb * BM;
  if (row0 >= offs[E_]) return;
  int e = 0;
#pragma unroll
  for (int i = 1; i < E_; ++i) if (row0 >= offs[i]) e = i;

  int t = threadIdx.x, l = t & 63, w = t >> 6;
  int wr = w >> 2, wc = w & 3;
  int srow = t >> 2;                           // 0..127 staging row
  int gsrc8 = ((l & 3) ^ ((l >> 3) & 3)) * 8;  // pre-swizzled source k-granule

  const _Float16* aP[AINS];
  if constexpr (MODE == 0) {
#pragma unroll
    for (int ins = 0; ins < AINS; ++ins) {
      int tk = slot_token[row0 + srow + ins * 128];
      aP[ins] = Amat + (size_t)tk * KD + gsrc8;
    }
  } else {
#pragma unroll
    for (int ins = 0; ins < AINS; ++ins)
      aP[ins] = Amat + (size_t)(row0 + srow + ins * 128) * KD + gsrc8;
  }
  const _Float16* b0P = Bmat + ((size_t)e * BEROWS + (size_t)nb * 256 + srow) * KD + gsrc8;
  const _Float16* b1P = b0P + (size_t)128 * KD;

  // proven 0-conflict read pattern: 16-row frags, granule kg = l>>4
  int fr = l & 15, kg = l >> 4;
  int swz8 = (kg ^ ((fr >> 1) & 3)) * 8;
  const int rA = (wr * 128 + fr) * 32 + swz8;
  const int rB = AH + (wc * 64 + fr) * 32 + swz8;

  f32x4 acc[MROW][4];
#pragma unroll
  for (int m = 0; m < MROW; ++m)
#pragma unroll
    for (int n = 0; n < 4; ++n) acc[m][n] = (f32x4){0.f, 0.f, 0.f, 0.f};

  // prologue: stage tiles 0 -> buf0, 1 -> buf1; wait tile 0 (tile 1 in flight)
#pragma unroll
  for (int ins = 0; ins < AINS; ++ins) gload16(aP[ins], &lds[ins * 4096 + w * 512]);
  gload16(b0P, &lds[AH + w * 512]);
  gload16(b1P, &lds[AH + 4096 + w * 512]);
#pragma unroll
  for (int ins = 0; ins < AINS; ++ins) gload16(aP[ins] + 32, &lds[BUFH + ins * 4096 + w * 512]);
  gload16(b0P + 32, &lds[BUFH + AH + w * 512]);
  gload16(b1P + 32, &lds[BUFH + AH + 4096 + w * 512]);
  asm volatile("s_waitcnt vmcnt(%0)" ::"i"(S) : "memory");
  __builtin_amdgcn_s_barrier();
  __builtin_amdgcn_sched_barrier(0);

  // advance source pointers to tile 2 (the first in-loop staged tile)
#pragma unroll
  for (int ins = 0; ins < AINS; ++ins) aP[ins] += 64;
  b0P += 64; b1P += 64;

#define GEMM_STEP(U, PRE2, WN)                                                        \
  {                                                                                   \
    constexpr int bi_ = (U) & 3;                                                      \
    constexpr int bs_ = ((U) + 2) & 3;                                                \
    if (PRE2) {                                                                       \
      _Pragma("unroll") for (int ins = 0; ins < AINS; ++ins)                          \
          gload16(aP[ins] + (U) * 32, &lds[bs_ * BUFH + ins * 4096 + w * 512]);       \
      gload16(b0P + (U) * 32, &lds[bs_ * BUFH + AH + w * 512]);                       \
      gload16(b1P + (U) * 32, &lds[bs_ * BUFH + AH + 4096 + w * 512]);                \
    }                                                                                 \
    half8 a_[MROW], b_[4];                                                            \
    _Pragma("unroll") for (int mi = 0; mi < MROW; ++mi)                               \
        a_[mi] = *(const half8*)&lds[bi_ * BUFH + rA + mi * 512];                     \
    _Pragma("unroll") for (int ni = 0; ni < 4; ++ni)                                  \
        b_[ni] = *(const half8*)&lds[bi_ * BUFH + rB + ni * 512];                     \
    __builtin_amdgcn_s_setprio(1);                                                    \
    _Pragma("unroll") for (int mi = 0; mi < MROW; ++mi)                               \
        _Pragma("unroll") for (int ni = 0; ni < 4; ++ni)                              \
            acc[mi][ni] = __builtin_amdgcn_mfma_f32_16x16x32_f16(a_[mi], b_[ni],      \
                                                                 acc[mi][ni], 0, 0, 0); \
    __builtin_amdgcn_s_setprio(0);                                                    \
    if ((WN) >= 0) {                                                                  \
      asm volatile("s_waitcnt vmcnt(%0)" ::"i"((WN) >= 0 ? (WN) : 0) : "memory");     \
      __builtin_amdgcn_s_barrier();                                                   \
      __builtin_amdgcn_sched_barrier(0);                                              \
    }                                                                                 \
  }

  for (int j4 = 0; j4 < NT - 4; j4 += 4) {
    GEMM_STEP(0, true, S)
    GEMM_STEP(1, true, S)
    GEMM_STEP(2, true, S)
    GEMM_STEP(3, true, S)
#pragma unroll
    for (int ins = 0; ins < AINS; ++ins) aP[ins] += 128;
    b0P += 128; b1P += 128;
  }
  // tail group (j = NT-4 .. NT-1): stage last two tiles, then drain
  GEMM_STEP(0, true, S)
  GEMM_STEP(1, true, S)
  GEMM_STEP(2, false, 0)
  GEMM_STEP(3, false, -1)
#undef GEMM_STEP

  // epilogue. C/D 16x16: col = lane&15, row = (lane>>4)*4 + i  [m89 verified]
  int q4 = kg * 4;
  if constexpr (MODE == 0) {
    _Float16* hb = (_Float16*)outp;
#pragma unroll
    for (int mi = 0; mi < MROW; ++mi) {
      size_t rbase = (size_t)(row0 + wr * 128 + mi * 16 + q4);
#pragma unroll
      for (int p = 0; p < 2; ++p) {
        int fc = nb * 128 + (wc * 2 + p) * 16 + fr;
#pragma unroll
        for (int i = 0; i < 4; ++i) {
          float gv = acc[mi][2 * p][i];
          float hv = gv / (1.f + __expf(-gv)) * acc[mi][2 * p + 1][i];
          hb[(rbase + i) * (size_t)F_ + fc] = (_Float16)hv;
        }
      }
    }
  } else {
    float* yb = (float*)outp;
#pragma unroll
    for (int mi = 0; mi < MROW; ++mi) {
      size_t rbase = (size_t)(row0 + wr * 128 + mi * 16 + q4);
#pragma unroll
      for (int ni = 0; ni < 4; ++ni) {
        int col = nb * 256 + wc * 64 + ni * 16 + fr;
#pragma unroll
        for (int i = 0; i < 4; ++i)
          yb[(rbase + i) * (size_t)D_ + col] = acc[mi][ni][i];
      }
    }
  }
}

// ---------------- combine ----------------
__global__ __launch_bounds__(256) void combine_kernel(
    const float* __restrict__ ybuf, const int* __restrict__ slot_of,
    const float* __restrict__ tok_g, float* __restrict__ out) {
  int t = blockIdx.x, i = threadIdx.x;
  int s0 = slot_of[t * 2], s1 = slot_of[t * 2 + 1];
  float g0 = tok_g[t * 2], g1 = tok_g[t * 2 + 1];
  float4 a = ((const float4*)(ybuf + (size_t)s0 * D_))[i];
  float4 b = ((const float4*)(ybuf + (size_t)s1 * D_))[i];
  float4 r;
  r.x = g0 * a.x + g1 * b.x;
  r.y = g0 * a.y + g1 * b.y;
  r.z = g0 * a.z + g1 * b.z;
  r.w = g0 * a.w + g1 * b.w;
  ((float4*)(out + (size_t)t * D_))[i] = r;
}

extern "C" void kernel_launch(void* const* d_in, const int* in_sizes, int n_in,
                              void* d_out, int out_size, void* d_ws, size_t ws_size,
                              hipStream_t stream) {
  const float* x  = (const float*)d_in[0];
  const float* rw = (const float*)d_in[1];
  const float* rbc = (const float*)d_in[2];
  const float* w1 = (const float*)d_in[3];
  const float* w2 = (const float*)d_in[4];  // dict order: w2 before w3
  const float* w3 = (const float*)d_in[5];
  float* out = (float*)d_out;

  char* ws = (char*)d_ws;
  size_t off = 0;
  auto take = [&](size_t bytes) {
    char* p = ws + off;
    off = (off + bytes + 255) & ~(size_t)255;
    return p;
  };
  _Float16* x16 = (_Float16*)take((size_t)NTOK * D_ * 2);
  _Float16* w13 = (_Float16*)take((size_t)E_ * 2 * F_ * D_ * 2);  // 128 MB
  _Float16* w2h = (_Float16*)take((size_t)E_ * D_ * F_ * 2);      // 64 MB
  _Float16* hbuf = (_Float16*)take((size_t)SLOT_CAP * F_ * 2);    // 151 MB
  float* ybuf = (float*)take((size_t)SLOT_CAP * D_ * 4);          // 75.5 MB
  int* slot_token = (int*)take((size_t)SLOT_CAP * 4);
  int* tok_e = (int*)take((size_t)NTOK * 2 * 4);
  float* tok_g = (float*)take((size_t)NTOK * 2 * 4);
  int* slot_of = (int*)take((size_t)NTOK * 2 * 4);
  int* counts = (int*)take(E_ * 4);
  int* cursor = (int*)take(E_ * 4);
  int* offs = (int*)take((E_ + 1) * 4);

  cvt_w13_kernel<<<4096, 256, 0, stream>>>(w1, w3, w13, E_ * F_ * D_ / 4);
  cvt_kernel<<<4096, 256, 0, stream>>>(w2, w2h, E_ * D_ * F_ / 4);
  init_kernel<<<(SLOT_CAP + 255) / 256, 256, 0, stream>>>(slot_token, counts, cursor);
  router_kernel<<<NTOK / 4, 256, 0, stream>>>(x, rw, rbc, x16, tok_e, tok_g, counts);
  scan_kernel<<<1, 64, 0, stream>>>(counts, offs);
  scatter_kernel<<<(NTOK * 2 + 255) / 256, 256, 0, stream>>>(tok_e, offs, cursor, slot_token, slot_of);
  // gemm1: 256x256, M<=18432 x Nvirt=8192 x K=1024 -> grid 8*9*32, ORD0 (share B)
  moe_gemm_kernel<0, 0, 1024, 32, 9, 8192><<<2304, 512, 0, stream>>>(
      x16, w13, slot_token, offs, (void*)hbuf);
  // gemm2: 256x256, M<=18432 x N=1024 x K=4096 -> grid 8*9*4, ORD1 (share A)
  moe_gemm_kernel<1, 1, 4096, 4, 9, 1024><<<288, 512, 0, stream>>>(
      hbuf, w2h, slot_token, offs, (void*)ybuf);
  combine_kernel<<<NTOK, 256, 0, stream>>>(ybuf, slot_of, tok_g, out);
}

// Round 7
// 912.478 us; speedup vs baseline: 1.0052x; 1.0052x over previous
//
#include <hip/hip_runtime.h>
#include <hip/hip_fp16.h>

// MoE top-2 SwiGLU, MI355X. Sparse grouped-GEMM, 256-aligned expert segments.
// Both GEMMs: 256x256 tile, 8 waves, 16x16x32 f16 MFMA, proven 0-conflict XOR
// swizzle (pre-swizzled global source), 4 LDS buffers, distance-3 gload prefetch,
// REGISTER-LEVEL frag pipeline: step j's MFMA stream overlaps ds_reads of step
// j+1's fragments (in-place, WAR-pinned), single lgkmcnt(0) drain per step,
// one barrier + counted vmcnt per K-step, setprio on MFMA, XCD-aware ordering.
// gemm1: virtual-N=8192 (w1/w3 interleaved 16-col) -> silu*mul -> h fp16. ORD0.
// gemm2: h @ w2^T -> y fp32, ORD1 (A-panel sharing per XCD). combine: gated sum.

#define NTOK 8192
#define D_ 1024
#define F_ 4096
#define E_ 8
#define SLOT_CAP 18432  // 2*8192 + 8*256

using half8 = __attribute__((ext_vector_type(8))) _Float16;
using half4 = __attribute__((ext_vector_type(4))) _Float16;
using f32x4 = __attribute__((ext_vector_type(4))) float;

__device__ __forceinline__ void gload16(const void* g, void* l) {
  __builtin_amdgcn_global_load_lds((const __attribute__((address_space(1))) void*)g,
                                   (__attribute__((address_space(3))) void*)l, 16, 0, 0);
}

// ---------------- fp32 -> fp16 convert ----------------
__global__ __launch_bounds__(256) void cvt_kernel(const float* __restrict__ src,
                                                  _Float16* __restrict__ dst, int n4) {
  int i = blockIdx.x * 256 + threadIdx.x;
  int stride = gridDim.x * 256;
  for (; i < n4; i += stride) {
    float4 v = ((const float4*)src)[i];
    half4 h;
    h.x = (_Float16)v.x; h.y = (_Float16)v.y; h.z = (_Float16)v.z; h.w = (_Float16)v.w;
    ((half4*)dst)[i] = h;
  }
}

// w1,w3 -> interleaved virtual rows w13[e][8192][1024]:
// vrow = ((f>>4)<<5) | (sel<<4) | (f&15); sel 0=w1(gate), 1=w3(up).
__global__ __launch_bounds__(256) void cvt_w13_kernel(const float* __restrict__ w1,
                                                      const float* __restrict__ w3,
                                                      _Float16* __restrict__ w13, int n4) {
  int i = blockIdx.x * 256 + threadIdx.x;
  int stride = gridDim.x * 256;
  for (; i < n4; i += stride) {
    int d4 = i & 255;   // D/4 = 256
    int row = i >> 8;   // e*4096 + f
    int e = row >> 12, f = row & 4095;
    size_t vbase = ((size_t)e << 13) | ((size_t)(f >> 4) << 5) | (size_t)(f & 15);
    float4 v1 = ((const float4*)w1)[i];
    float4 v3 = ((const float4*)w3)[i];
    half4 h1, h3;
    h1.x = (_Float16)v1.x; h1.y = (_Float16)v1.y; h1.z = (_Float16)v1.z; h1.w = (_Float16)v1.w;
    h3.x = (_Float16)v3.x; h3.y = (_Float16)v3.y; h3.z = (_Float16)v3.z; h3.w = (_Float16)v3.w;
    ((half4*)w13)[vbase * 256 + d4] = h1;
    ((half4*)w13)[(vbase + 16) * 256 + d4] = h3;
  }
}

// ---------------- router (+ fused x fp32->fp16) ----------------
__global__ __launch_bounds__(256) void router_kernel(
    const float* __restrict__ x, const float* __restrict__ rw, const float* __restrict__ rbias,
    _Float16* __restrict__ x16, int* __restrict__ tok_e, float* __restrict__ tok_g,
    int* __restrict__ counts) {
  int wv = threadIdx.x >> 6, lane = threadIdx.x & 63;
  int t = blockIdx.x * 4 + wv;
  const float4* xr = (const float4*)(x + (size_t)t * D_);
  float acc[E_];
#pragma unroll
  for (int e = 0; e < E_; ++e) acc[e] = 0.f;
  for (int i = lane; i < D_ / 4; i += 64) {
    float4 xv = xr[i];
    half4 hx;
    hx.x = (_Float16)xv.x; hx.y = (_Float16)xv.y; hx.z = (_Float16)xv.z; hx.w = (_Float16)xv.w;
    ((half4*)(x16 + (size_t)t * D_))[i] = hx;
#pragma unroll
    for (int e = 0; e < E_; ++e) {
      float4 wv4 = ((const float4*)(rw + (size_t)e * D_))[i];
      acc[e] += xv.x * wv4.x + xv.y * wv4.y + xv.z * wv4.z + xv.w * wv4.w;
    }
  }
#pragma unroll
  for (int e = 0; e < E_; ++e) {
#pragma unroll
    for (int off = 32; off > 0; off >>= 1) acc[e] += __shfl_down(acc[e], off);
  }
  if (lane == 0) {
    float p[E_], mx = -1e30f;
#pragma unroll
    for (int e = 0; e < E_; ++e) { p[e] = acc[e] + rbias[e]; mx = fmaxf(mx, p[e]); }
#pragma unroll
    for (int e = 0; e < E_; ++e) p[e] = expf(p[e] - mx);
    int i0 = 0;
#pragma unroll
    for (int e = 1; e < E_; ++e) if (p[e] > p[i0]) i0 = e;
    int i1 = (i0 == 0) ? 1 : 0;
#pragma unroll
    for (int e = 0; e < E_; ++e) if (e != i0 && p[e] > p[i1]) i1 = e;
    float s = p[i0] + p[i1];
    tok_e[t * 2] = i0; tok_e[t * 2 + 1] = i1;
    tok_g[t * 2] = p[i0] / s; tok_g[t * 2 + 1] = p[i1] / s;
    atomicAdd(&counts[i0], 1); atomicAdd(&counts[i1], 1);
  }
}

__global__ void init_kernel(int* slot_token, int* counts, int* cursor) {
  int i = blockIdx.x * 256 + threadIdx.x;
  if (blockIdx.x == 0 && threadIdx.x < E_) { counts[threadIdx.x] = 0; cursor[threadIdx.x] = 0; }
  if (i < SLOT_CAP) slot_token[i] = 0;  // padding -> token 0 (never combined)
}

__global__ void scan_kernel(const int* __restrict__ counts, int* __restrict__ offs) {
  if (threadIdx.x == 0) {
    int o = 0;
    for (int e = 0; e < E_; ++e) { offs[e] = o; o += ((counts[e] + 255) / 256) * 256; }
    offs[E_] = o;
  }
}

__global__ void scatter_kernel(const int* __restrict__ tok_e, const int* __restrict__ offs,
                               int* __restrict__ cursor, int* __restrict__ slot_token,
                               int* __restrict__ slot_of) {
  int i = blockIdx.x * 256 + threadIdx.x;
  if (i >= NTOK * 2) return;
  int e = tok_e[i];
  int pos = offs[e] + atomicAdd(&cursor[e], 1);
  slot_token[pos] = i >> 1;
  slot_of[i] = pos;
}

// ---------------- pipelined grouped GEMM (16x16x32 f16, BM=256, BN=256) ----------------
template <int MODE, int ORD, int KD, int NBN, int RPX, int BEROWS>
__global__ __launch_bounds__(512, 2) void moe_gemm_kernel(
    const _Float16* __restrict__ Amat, const _Float16* __restrict__ Bmat,
    const int* __restrict__ slot_token, const int* __restrict__ offs,
    void* __restrict__ outp) {
  constexpr int BM = 256;
  constexpr int MROW = 8;               // 16-row m-frags per wave
  constexpr int AH = BM * 32;           // A halves per buffer (8192)
  constexpr int BUFH = (BM + 256) * 32; // 16384 halves = 32 KB
  constexpr int NT = KD / 32;           // K-steps (multiple of 4, >= 8)
  __shared__ _Float16 lds[4 * BUFH];    // 128 KB

  int id = blockIdx.x;
  int xcd = id & 7, idx = id >> 3;  // grid = 8 * RPX * NBN
  int rb, nb;
  if constexpr (ORD == 0) {
    int band = idx / (8 * NBN);
    int i2 = idx - band * (8 * NBN);
    int rib = (RPX - band * 8) < 8 ? (RPX - band * 8) : 8;
    nb = i2 / rib;
    rb = xcd * RPX + band * 8 + (i2 - nb * rib);
  } else {
    nb = idx % NBN;
    rb = xcd * RPX + idx / NBN;
  }
  int row0 = rb * BM;
  if (row0 >= offs[E_]) return;
  int e = 0;
#pragma unroll
  for (int i = 1; i < E_; ++i) if (row0 >= offs[i]) e = i;

  int t = threadIdx.x, l = t & 63, w = t >> 6;
  int wr = w >> 2, wc = w & 3;
  int srow = t >> 2;                           // 0..127 staging row
  int gsrc8 = ((l & 3) ^ ((l >> 3) & 3)) * 8;  // pre-swizzled source k-granule

  const _Float16* aP0;
  const _Float16* aP1;
  if constexpr (MODE == 0) {
    int tk0 = slot_token[row0 + srow];
    int tk1 = slot_token[row0 + srow + 128];
    aP0 = Amat + (size_t)tk0 * KD + gsrc8;
    aP1 = Amat + (size_t)tk1 * KD + gsrc8;
  } else {
    aP0 = Amat + (size_t)(row0 + srow) * KD + gsrc8;
    aP1 = Amat + (size_t)(row0 + srow + 128) * KD + gsrc8;
  }
  const _Float16* b0P = Bmat + ((size_t)e * BEROWS + (size_t)nb * 256 + srow) * KD + gsrc8;
  const _Float16* b1P = b0P + (size_t)128 * KD;

  // proven 0-conflict read pattern: 16-row frags, granule kg = l>>4
  int fr = l & 15, kg = l >> 4;
  int swz8 = (kg ^ ((fr >> 1) & 3)) * 8;
  const int rA = (wr * 128 + fr) * 32 + swz8;
  const int rB = AH + (wc * 64 + fr) * 32 + swz8;

  half8 aF[MROW];
  half8 bF[4];
  f32x4 acc[MROW][4];
#pragma unroll
  for (int m = 0; m < MROW; ++m)
#pragma unroll
    for (int n = 0; n < 4; ++n) acc[m][n] = (f32x4){0.f, 0.f, 0.f, 0.f};

  // prologue: stage tiles 0,1,2 into buf0..2; wait tiles 0,1 (tile 2 in flight)
#pragma unroll
  for (int tt = 0; tt < 3; ++tt) {
    gload16(aP0 + tt * 32, &lds[tt * BUFH + w * 512]);
    gload16(aP1 + tt * 32, &lds[tt * BUFH + 4096 + w * 512]);
    gload16(b0P + tt * 32, &lds[tt * BUFH + AH + w * 512]);
    gload16(b1P + tt * 32, &lds[tt * BUFH + AH + 4096 + w * 512]);
  }
  asm volatile("s_waitcnt vmcnt(4)" ::: "memory");
  __builtin_amdgcn_s_barrier();
  __builtin_amdgcn_sched_barrier(0);
  // read frags(0) from buf0
#pragma unroll
  for (int m = 0; m < MROW; ++m) aF[m] = *(const half8*)&lds[rA + m * 512];
#pragma unroll
  for (int n = 0; n < 4; ++n) bF[n] = *(const half8*)&lds[rB + n * 512];
  __builtin_amdgcn_sched_barrier(0);
  // advance source pointers to tile 3 (first in-loop staged tile)
  aP0 += 96; aP1 += 96; b0P += 96; b1P += 96;

#define MF4_(mm)                                                                         \
  acc[mm][0] = __builtin_amdgcn_mfma_f32_16x16x32_f16(aF[mm], bF[0], acc[mm][0], 0, 0, 0); \
  acc[mm][1] = __builtin_amdgcn_mfma_f32_16x16x32_f16(aF[mm], bF[1], acc[mm][1], 0, 0, 0); \
  acc[mm][2] = __builtin_amdgcn_mfma_f32_16x16x32_f16(aF[mm], bF[2], acc[mm][2], 0, 0, 0); \
  acc[mm][3] = __builtin_amdgcn_mfma_f32_16x16x32_f16(aF[mm], bF[3], acc[mm][3], 0, 0, 0);

// step j = group base + U. Stage tile j+3, drain last step's frag reads,
// MFMA stream with next-step frag reads interleaved in place (WAR-pinned).
#define GSTEP(U, PRE, WN)                                                     \
  {                                                                           \
    constexpr int bn_ = ((U) + 1) & 3;                                        \
    constexpr int bs_ = ((U) + 3) & 3;                                        \
    if (PRE) {                                                                \
      gload16(aP0 + (U) * 32, &lds[bs_ * BUFH + w * 512]);                    \
      gload16(aP1 + (U) * 32, &lds[bs_ * BUFH + 4096 + w * 512]);             \
      gload16(b0P + (U) * 32, &lds[bs_ * BUFH + AH + w * 512]);               \
      gload16(b1P + (U) * 32, &lds[bs_ * BUFH + AH + 4096 + w * 512]);        \
    }                                                                         \
    const _Float16* nb_ = &lds[bn_ * BUFH];                                   \
    asm volatile("s_waitcnt lgkmcnt(0)" ::: "memory");                        \
    __builtin_amdgcn_sched_barrier(0);                                        \
    __builtin_amdgcn_s_setprio(1);                                            \
    MF4_(0) aF[0] = *(const half8*)(nb_ + rA);                                \
    MF4_(1) aF[1] = *(const half8*)(nb_ + rA + 512);                          \
    MF4_(2) aF[2] = *(const half8*)(nb_ + rA + 1024);                         \
    MF4_(3) aF[3] = *(const half8*)(nb_ + rA + 1536);                         \
    MF4_(4) aF[4] = *(const half8*)(nb_ + rA + 2048);                         \
    MF4_(5) aF[5] = *(const half8*)(nb_ + rA + 2560);                         \
    MF4_(6) aF[6] = *(const half8*)(nb_ + rA + 3072);                         \
    MF4_(7) aF[7] = *(const half8*)(nb_ + rA + 3584);                         \
    bF[0] = *(const half8*)(nb_ + rB);                                        \
    bF[1] = *(const half8*)(nb_ + rB + 512);                                  \
    bF[2] = *(const half8*)(nb_ + rB + 1024);                                 \
    bF[3] = *(const half8*)(nb_ + rB + 1536);                                 \
    __builtin_amdgcn_s_setprio(0);                                            \
    if ((WN) >= 0) {                                                          \
      asm volatile("s_waitcnt vmcnt(%0)" ::"i"((WN) >= 0 ? (WN) : 0) : "memory"); \
      __builtin_amdgcn_s_barrier();                                           \
      __builtin_amdgcn_sched_barrier(0);                                      \
    }                                                                         \
  }

  for (int j4 = 0; j4 < NT - 4; j4 += 4) {
    GSTEP(0, true, 4)
    GSTEP(1, true, 4)
    GSTEP(2, true, 4)
    GSTEP(3, true, 4)
    aP0 += 128; aP1 += 128; b0P += 128; b1P += 128;
  }
  // tail group: steps NT-4 .. NT-1
  GSTEP(0, true, 4)    // stages tile NT-1; tile NT-2 resident after
  GSTEP(1, false, 0)   // drain stage(NT-1) -> tile NT-1 resident
  GSTEP(2, false, -1)  // reads frags(NT-1); no more LDS writes -> no barrier
  // final step: no next-tile reads
  asm volatile("s_waitcnt lgkmcnt(0)" ::: "memory");
  __builtin_amdgcn_sched_barrier(0);
  __builtin_amdgcn_s_setprio(1);
  MF4_(0) MF4_(1) MF4_(2) MF4_(3) MF4_(4) MF4_(5) MF4_(6) MF4_(7)
  __builtin_amdgcn_s_setprio(0);
#undef GSTEP
#undef MF4_

  // epilogue. C/D 16x16: col = lane&15, row = (lane>>4)*4 + i  [m89 verified]
  int q4 = kg * 4;
  if constexpr (MODE == 0) {
    _Float16* hb = (_Float16*)outp;
#pragma unroll
    for (int mi = 0; mi < MROW; ++mi) {
      size_t rbase = (size_t)(row0 + wr * 128 + mi * 16 + q4);
#pragma unroll
      for (int p = 0; p < 2; ++p) {
        int fc = nb * 128 + (wc * 2 + p) * 16 + fr;
#pragma unroll
        for (int i = 0; i < 4; ++i) {
          float gv = acc[mi][2 * p][i];
          float hv = gv / (1.f + __expf(-gv)) * acc[mi][2 * p + 1][i];
          hb[(rbase + i) * (size_t)F_ + fc] = (_Float16)hv;
        }
      }
    }
  } else {
    float* yb = (float*)outp;
#pragma unroll
    for (int mi = 0; mi < MROW; ++mi) {
      size_t rbase = (size_t)(row0 + wr * 128 + mi * 16 + q4);
#pragma unroll
      for (int ni = 0; ni < 4; ++ni) {
        int col = nb * 256 + wc * 64 + ni * 16 + fr;
#pragma unroll
        for (int i = 0; i < 4; ++i)
          yb[(rbase + i) * (size_t)D_ + col] = acc[mi][ni][i];
      }
    }
  }
}

// ---------------- combine ----------------
__global__ __launch_bounds__(256) void combine_kernel(
    const float* __restrict__ ybuf, const int* __restrict__ slot_of,
    const float* __restrict__ tok_g, float* __restrict__ out) {
  int t = blockIdx.x, i = threadIdx.x;
  int s0 = slot_of[t * 2], s1 = slot_of[t * 2 + 1];
  float g0 = tok_g[t * 2], g1 = tok_g[t * 2 + 1];
  float4 a = ((const float4*)(ybuf + (size_t)s0 * D_))[i];
  float4 b = ((const float4*)(ybuf + (size_t)s1 * D_))[i];
  float4 r;
  r.x = g0 * a.x + g1 * b.x;
  r.y = g0 * a.y + g1 * b.y;
  r.z = g0 * a.z + g1 * b.z;
  r.w = g0 * a.w + g1 * b.w;
  ((float4*)(out + (size_t)t * D_))[i] = r;
}

extern "C" void kernel_launch(void* const* d_in, const int* in_sizes, int n_in,
                              void* d_out, int out_size, void* d_ws, size_t ws_size,
                              hipStream_t stream) {
  const float* x  = (const float*)d_in[0];
  const float* rw = (const float*)d_in[1];
  const float* rbc = (const float*)d_in[2];
  const float* w1 = (const float*)d_in[3];
  const float* w2 = (const float*)d_in[4];  // dict order: w2 before w3
  const float* w3 = (const float*)d_in[5];
  float* out = (float*)d_out;

  char* ws = (char*)d_ws;
  size_t off = 0;
  auto take = [&](size_t bytes) {
    char* p = ws + off;
    off = (off + bytes + 255) & ~(size_t)255;
    return p;
  };
  _Float16* x16 = (_Float16*)take((size_t)NTOK * D_ * 2);
  _Float16* w13 = (_Float16*)take((size_t)E_ * 2 * F_ * D_ * 2);  // 128 MB
  _Float16* w2h = (_Float16*)take((size_t)E_ * D_ * F_ * 2);      // 64 MB
  _Float16* hbuf = (_Float16*)take((size_t)SLOT_CAP * F_ * 2);    // 151 MB
  float* ybuf = (float*)take((size_t)SLOT_CAP * D_ * 4);          // 75.5 MB
  int* slot_token = (int*)take((size_t)SLOT_CAP * 4);
  int* tok_e = (int*)take((size_t)NTOK * 2 * 4);
  float* tok_g = (float*)take((size_t)NTOK * 2 * 4);
  int* slot_of = (int*)take((size_t)NTOK * 2 * 4);
  int* counts = (int*)take(E_ * 4);
  int* cursor = (int*)take(E_ * 4);
  int* offs = (int*)take((E_ + 1) * 4);

  cvt_w13_kernel<<<4096, 256, 0, stream>>>(w1, w3, w13, E_ * F_ * D_ / 4);
  cvt_kernel<<<4096, 256, 0, stream>>>(w2, w2h, E_ * D_ * F_ / 4);
  init_kernel<<<(SLOT_CAP + 255) / 256, 256, 0, stream>>>(slot_token, counts, cursor);
  router_kernel<<<NTOK / 4, 256, 0, stream>>>(x, rw, rbc, x16, tok_e, tok_g, counts);
  scan_kernel<<<1, 64, 0, stream>>>(counts, offs);
  scatter_kernel<<<(NTOK * 2 + 255) / 256, 256, 0, stream>>>(tok_e, offs, cursor, slot_token, slot_of);
  // gemm1: 256x256, M<=18432 x Nvirt=8192 x K=1024 -> grid 8*9*32, ORD0 (share B)
  moe_gemm_kernel<0, 0, 1024, 32, 9, 8192><<<2304, 512, 0, stream>>>(
      x16, w13, slot_token, offs, (void*)hbuf);
  // gemm2: 256x256, M<=18432 x N=1024 x K=4096 -> grid 8*9*4, ORD1 (share A)
  moe_gemm_kernel<1, 1, 4096, 4, 9, 1024><<<288, 512, 0, stream>>>(
      hbuf, w2h, slot_token, offs, (void*)ybuf);
  combine_kernel<<<NTOK, 256, 0, stream>>>(ybuf, slot_of, tok_g, out);
}

// Round 8
// 900.658 us; speedup vs baseline: 1.0184x; 1.0131x over previous
//
#include <hip/hip_runtime.h>
#include <hip/hip_fp16.h>

// MoE top-2 SwiGLU, MI355X. Sparse grouped-GEMM, 256-aligned expert segments.
// Both GEMMs: 256x256 tile, 8 waves, 16x16x32 f16 MFMA, proven 0-conflict XOR
// swizzle (pre-swizzled global source), 4 LDS buffers, distance-3 gload prefetch,
// SGB-pinned software pipeline: B-frags double-buffered in regs, step j issues
// next-step frag reads EARLY inside the MFMA stream ({MFMA4,DS1}x8 pinning),
// compiler auto-waitcnt gives counted lgkm sync; boundary = vmcnt(4)+barrier.
// gemm1: virtual-N=8192 (w1/w3 interleaved 16-col) -> silu*mul -> h fp16. ORD0.
// gemm2: h @ w2^T, split-K=2 (partials ybuf + reused-w13), ORD1. combine: gated sum.

#define NTOK 8192
#define D_ 1024
#define F_ 4096
#define E_ 8
#define SLOT_CAP 18432  // 2*8192 + 8*256

using half8 = __attribute__((ext_vector_type(8))) _Float16;
using half4 = __attribute__((ext_vector_type(4))) _Float16;
using f32x4 = __attribute__((ext_vector_type(4))) float;

__device__ __forceinline__ void gload16(const void* g, void* l) {
  __builtin_amdgcn_global_load_lds((const __attribute__((address_space(1))) void*)g,
                                   (__attribute__((address_space(3))) void*)l, 16, 0, 0);
}

// ---------------- fp32 -> fp16 convert ----------------
__global__ __launch_bounds__(256) void cvt_kernel(const float* __restrict__ src,
                                                  _Float16* __restrict__ dst, int n4) {
  int i = blockIdx.x * 256 + threadIdx.x;
  int stride = gridDim.x * 256;
  for (; i < n4; i += stride) {
    float4 v = ((const float4*)src)[i];
    half4 h;
    h.x = (_Float16)v.x; h.y = (_Float16)v.y; h.z = (_Float16)v.z; h.w = (_Float16)v.w;
    ((half4*)dst)[i] = h;
  }
}

// w1,w3 -> interleaved virtual rows w13[e][8192][1024]:
// vrow = ((f>>4)<<5) | (sel<<4) | (f&15); sel 0=w1(gate), 1=w3(up).
__global__ __launch_bounds__(256) void cvt_w13_kernel(const float* __restrict__ w1,
                                                      const float* __restrict__ w3,
                                                      _Float16* __restrict__ w13, int n4) {
  int i = blockIdx.x * 256 + threadIdx.x;
  int stride = gridDim.x * 256;
  for (; i < n4; i += stride) {
    int d4 = i & 255;   // D/4 = 256
    int row = i >> 8;   // e*4096 + f
    int e = row >> 12, f = row & 4095;
    size_t vbase = ((size_t)e << 13) | ((size_t)(f >> 4) << 5) | (size_t)(f & 15);
    float4 v1 = ((const float4*)w1)[i];
    float4 v3 = ((const float4*)w3)[i];
    half4 h1, h3;
    h1.x = (_Float16)v1.x; h1.y = (_Float16)v1.y; h1.z = (_Float16)v1.z; h1.w = (_Float16)v1.w;
    h3.x = (_Float16)v3.x; h3.y = (_Float16)v3.y; h3.z = (_Float16)v3.z; h3.w = (_Float16)v3.w;
    ((half4*)w13)[vbase * 256 + d4] = h1;
    ((half4*)w13)[(vbase + 16) * 256 + d4] = h3;
  }
}

// ---------------- router (+ fused x fp32->fp16) ----------------
__global__ __launch_bounds__(256) void router_kernel(
    const float* __restrict__ x, const float* __restrict__ rw, const float* __restrict__ rbias,
    _Float16* __restrict__ x16, int* __restrict__ tok_e, float* __restrict__ tok_g,
    int* __restrict__ counts) {
  int wv = threadIdx.x >> 6, lane = threadIdx.x & 63;
  int t = blockIdx.x * 4 + wv;
  const float4* xr = (const float4*)(x + (size_t)t * D_);
  float acc[E_];
#pragma unroll
  for (int e = 0; e < E_; ++e) acc[e] = 0.f;
  for (int i = lane; i < D_ / 4; i += 64) {
    float4 xv = xr[i];
    half4 hx;
    hx.x = (_Float16)xv.x; hx.y = (_Float16)xv.y; hx.z = (_Float16)xv.z; hx.w = (_Float16)xv.w;
    ((half4*)(x16 + (size_t)t * D_))[i] = hx;
#pragma unroll
    for (int e = 0; e < E_; ++e) {
      float4 wv4 = ((const float4*)(rw + (size_t)e * D_))[i];
      acc[e] += xv.x * wv4.x + xv.y * wv4.y + xv.z * wv4.z + xv.w * wv4.w;
    }
  }
#pragma unroll
  for (int e = 0; e < E_; ++e) {
#pragma unroll
    for (int off = 32; off > 0; off >>= 1) acc[e] += __shfl_down(acc[e], off);
  }
  if (lane == 0) {
    float p[E_], mx = -1e30f;
#pragma unroll
    for (int e = 0; e < E_; ++e) { p[e] = acc[e] + rbias[e]; mx = fmaxf(mx, p[e]); }
#pragma unroll
    for (int e = 0; e < E_; ++e) p[e] = expf(p[e] - mx);
    int i0 = 0;
#pragma unroll
    for (int e = 1; e < E_; ++e) if (p[e] > p[i0]) i0 = e;
    int i1 = (i0 == 0) ? 1 : 0;
#pragma unroll
    for (int e = 0; e < E_; ++e) if (e != i0 && p[e] > p[i1]) i1 = e;
    float s = p[i0] + p[i1];
    tok_e[t * 2] = i0; tok_e[t * 2 + 1] = i1;
    tok_g[t * 2] = p[i0] / s; tok_g[t * 2 + 1] = p[i1] / s;
    atomicAdd(&counts[i0], 1); atomicAdd(&counts[i1], 1);
  }
}

__global__ void init_kernel(int* slot_token, int* counts, int* cursor) {
  int i = blockIdx.x * 256 + threadIdx.x;
  if (blockIdx.x == 0 && threadIdx.x < E_) { counts[threadIdx.x] = 0; cursor[threadIdx.x] = 0; }
  if (i < SLOT_CAP) slot_token[i] = 0;  // padding -> token 0 (never combined)
}

__global__ void scan_kernel(const int* __restrict__ counts, int* __restrict__ offs) {
  if (threadIdx.x == 0) {
    int o = 0;
    for (int e = 0; e < E_; ++e) { offs[e] = o; o += ((counts[e] + 255) / 256) * 256; }
    offs[E_] = o;
  }
}

__global__ void scatter_kernel(const int* __restrict__ tok_e, const int* __restrict__ offs,
                               int* __restrict__ cursor, int* __restrict__ slot_token,
                               int* __restrict__ slot_of) {
  int i = blockIdx.x * 256 + threadIdx.x;
  if (i >= NTOK * 2) return;
  int e = tok_e[i];
  int pos = offs[e] + atomicAdd(&cursor[e], 1);
  slot_token[pos] = i >> 1;
  slot_of[i] = pos;
}

// ---------------- pipelined grouped GEMM (16x16x32 f16, BM=256, BN=256) ----------------
template <int MODE, int ORD, int KSPLIT, int KD, int NBN, int RPX, int BEROWS>
__global__ __launch_bounds__(512, 2) void moe_gemm_kernel(
    const _Float16* __restrict__ Amat, const _Float16* __restrict__ Bmat,
    const int* __restrict__ slot_token, const int* __restrict__ offs,
    void* __restrict__ outp, void* __restrict__ outp2) {
  constexpr int BM = 256;
  constexpr int MROW = 8;               // 16-row m-frags per wave
  constexpr int AH = BM * 32;           // A halves per buffer (8192)
  constexpr int BUFH = (BM + 256) * 32; // 16384 halves = 32 KB
  constexpr int KL = KD / KSPLIT;       // K span per block
  constexpr int NT = KL / 32;           // K-steps (multiple of 4, >= 8)
  __shared__ _Float16 lds[4 * BUFH];    // 128 KB

  int id = blockIdx.x;
  int xcd = id & 7, idx = id >> 3;  // grid = 8 * RPX * NBN
  int vr, nb;
  if constexpr (ORD == 0) {
    int band = idx / (8 * NBN);
    int i2 = idx - band * (8 * NBN);
    int rib = (RPX - band * 8) < 8 ? (RPX - band * 8) : 8;
    nb = i2 / rib;
    vr = xcd * RPX + band * 8 + (i2 - nb * rib);
  } else {
    nb = idx % NBN;
    vr = xcd * RPX + idx / NBN;
  }
  int rb = vr, ks = 0;
  if constexpr (KSPLIT == 2) { rb = vr >> 1; ks = vr & 1; }
  int row0 = rb * BM;
  if (row0 >= offs[E_]) return;
  int e = 0;
#pragma unroll
  for (int i = 1; i < E_; ++i) if (row0 >= offs[i]) e = i;
  int koff = ks * KL;

  int t = threadIdx.x, l = t & 63, w = t >> 6;
  int wr = w >> 2, wc = w & 3;
  int srow = t >> 2;                           // 0..127 staging row
  int gsrc8 = ((l & 3) ^ ((l >> 3) & 3)) * 8;  // pre-swizzled source k-granule

  const _Float16* aP0;
  const _Float16* aP1;
  if constexpr (MODE == 0) {
    int tk0 = slot_token[row0 + srow];
    int tk1 = slot_token[row0 + srow + 128];
    aP0 = Amat + (size_t)tk0 * KD + koff + gsrc8;
    aP1 = Amat + (size_t)tk1 * KD + koff + gsrc8;
  } else {
    aP0 = Amat + (size_t)(row0 + srow) * KD + koff + gsrc8;
    aP1 = Amat + (size_t)(row0 + srow + 128) * KD + koff + gsrc8;
  }
  const _Float16* b0P =
      Bmat + ((size_t)e * BEROWS + (size_t)nb * 256 + srow) * KD + koff + gsrc8;
  const _Float16* b1P = b0P + (size_t)128 * KD;

  // proven 0-conflict read pattern: 16-row frags, granule kg = l>>4
  int fr = l & 15, kg = l >> 4;
  int swz8 = (kg ^ ((fr >> 1) & 3)) * 8;
  const int rA = (wr * 128 + fr) * 32 + swz8;
  const int rB = AH + (wc * 64 + fr) * 32 + swz8;

  half8 aF[MROW];
  half8 bF[4], bF2[4];
  f32x4 acc[MROW][4];
#pragma unroll
  for (int m = 0; m < MROW; ++m)
#pragma unroll
    for (int n = 0; n < 4; ++n) acc[m][n] = (f32x4){0.f, 0.f, 0.f, 0.f};

  // prologue: stage tiles 0,1,2 into buf0..2; wait tiles 0,1 (tile 2 in flight)
#pragma unroll
  for (int tt = 0; tt < 3; ++tt) {
    gload16(aP0 + tt * 32, &lds[tt * BUFH + w * 512]);
    gload16(aP1 + tt * 32, &lds[tt * BUFH + 4096 + w * 512]);
    gload16(b0P + tt * 32, &lds[tt * BUFH + AH + w * 512]);
    gload16(b1P + tt * 32, &lds[tt * BUFH + AH + 4096 + w * 512]);
  }
  asm volatile("s_waitcnt vmcnt(4)" ::: "memory");
  __builtin_amdgcn_s_barrier();
  __builtin_amdgcn_sched_barrier(0);
  // read frags(0) from buf0 (step 0 uses bF)
#pragma unroll
  for (int m = 0; m < MROW; ++m) aF[m] = *(const half8*)&lds[rA + m * 512];
#pragma unroll
  for (int n = 0; n < 4; ++n) bF[n] = *(const half8*)&lds[rB + n * 512];
  __builtin_amdgcn_sched_barrier(0);
  // advance source pointers to tile 3 (first in-loop staged tile)
  aP0 += 96; aP1 += 96; b0P += 96; b1P += 96;

#define SGB_(m, n) __builtin_amdgcn_sched_group_barrier(m, n, 0)
#define MF4B(mm, BU)                                                                       \
  acc[mm][0] = __builtin_amdgcn_mfma_f32_16x16x32_f16(aF[mm], BU[0], acc[mm][0], 0, 0, 0); \
  acc[mm][1] = __builtin_amdgcn_mfma_f32_16x16x32_f16(aF[mm], BU[1], acc[mm][1], 0, 0, 0); \
  acc[mm][2] = __builtin_amdgcn_mfma_f32_16x16x32_f16(aF[mm], BU[2], acc[mm][2], 0, 0, 0); \
  acc[mm][3] = __builtin_amdgcn_mfma_f32_16x16x32_f16(aF[mm], BU[3], acc[mm][3], 0, 0, 0);

// step j (= group base + U). Uses BU frags (read last step); reads next-step
// frags into BR (B first — no WAR) and aF (in place, after each cluster).
// SGB pins [VMEM4][DS4][{MFMA4,DS1}x8]; compiler auto-waitcnt does counted sync.
#define GSTEP(U, PRE, WN, BU, BR)                                                 \
  {                                                                               \
    constexpr int bn_ = ((U) + 1) & 3;                                            \
    constexpr int bs_ = ((U) + 3) & 3;                                            \
    __builtin_amdgcn_s_setprio(1);                                                \
    if (PRE) {                                                                    \
      gload16(aP0 + (U) * 32, &lds[bs_ * BUFH + w * 512]);                        \
      gload16(aP1 + (U) * 32, &lds[bs_ * BUFH + 4096 + w * 512]);                 \
      gload16(b0P + (U) * 32, &lds[bs_ * BUFH + AH + w * 512]);                   \
      gload16(b1P + (U) * 32, &lds[bs_ * BUFH + AH + 4096 + w * 512]);            \
    }                                                                             \
    const _Float16* nb_ = &lds[bn_ * BUFH];                                       \
    BR[0] = *(const half8*)(nb_ + rB);                                            \
    BR[1] = *(const half8*)(nb_ + rB + 512);                                      \
    BR[2] = *(const half8*)(nb_ + rB + 1024);                                     \
    BR[3] = *(const half8*)(nb_ + rB + 1536);                                     \
    MF4B(0, BU) aF[0] = *(const half8*)(nb_ + rA);                                \
    MF4B(1, BU) aF[1] = *(const half8*)(nb_ + rA + 512);                          \
    MF4B(2, BU) aF[2] = *(const half8*)(nb_ + rA + 1024);                         \
    MF4B(3, BU) aF[3] = *(const half8*)(nb_ + rA + 1536);                         \
    MF4B(4, BU) aF[4] = *(const half8*)(nb_ + rA + 2048);                         \
    MF4B(5, BU) aF[5] = *(const half8*)(nb_ + rA + 2560);                         \
    MF4B(6, BU) aF[6] = *(const half8*)(nb_ + rA + 3072);                         \
    MF4B(7, BU) aF[7] = *(const half8*)(nb_ + rA + 3584);                         \
    if (PRE) SGB_(0x20, 4);                                                       \
    SGB_(0x100, 4);                                                               \
    SGB_(0x8, 4); SGB_(0x100, 1);                                                 \
    SGB_(0x8, 4); SGB_(0x100, 1);                                                 \
    SGB_(0x8, 4); SGB_(0x100, 1);                                                 \
    SGB_(0x8, 4); SGB_(0x100, 1);                                                 \
    SGB_(0x8, 4); SGB_(0x100, 1);                                                 \
    SGB_(0x8, 4); SGB_(0x100, 1);                                                 \
    SGB_(0x8, 4); SGB_(0x100, 1);                                                 \
    SGB_(0x8, 4); SGB_(0x100, 1);                                                 \
    __builtin_amdgcn_s_setprio(0);                                                \
    if ((WN) >= 0) {                                                              \
      asm volatile("s_waitcnt vmcnt(%0)" ::"i"((WN) >= 0 ? (WN) : 0) : "memory"); \
      __builtin_amdgcn_s_barrier();                                               \
      __builtin_amdgcn_sched_barrier(0);                                          \
    }                                                                             \
  }

  for (int j4 = 0; j4 < NT - 4; j4 += 4) {
    GSTEP(0, true, 4, bF, bF2)
    GSTEP(1, true, 4, bF2, bF)
    GSTEP(2, true, 4, bF, bF2)
    GSTEP(3, true, 4, bF2, bF)
    aP0 += 128; aP1 += 128; b0P += 128; b1P += 128;
  }
  // tail: steps NT-4 .. NT-1
  GSTEP(0, true, 4, bF, bF2)   // stages tile NT-1
  GSTEP(1, false, 0, bF2, bF)  // drain staging -> tile NT-1 resident
  GSTEP(2, false, -1, bF, bF2) // reads frags(NT-1); no more LDS writes
  __builtin_amdgcn_s_setprio(1);
  MF4B(0, bF2) MF4B(1, bF2) MF4B(2, bF2) MF4B(3, bF2)
  MF4B(4, bF2) MF4B(5, bF2) MF4B(6, bF2) MF4B(7, bF2)
  __builtin_amdgcn_s_setprio(0);
#undef GSTEP
#undef MF4B
#undef SGB_

  // epilogue. C/D 16x16: col = lane&15, row = (lane>>4)*4 + i  [m89 verified]
  int q4 = kg * 4;
  if constexpr (MODE == 0) {
    _Float16* hb = (_Float16*)outp;
#pragma unroll
    for (int mi = 0; mi < MROW; ++mi) {
      size_t rbase = (size_t)(row0 + wr * 128 + mi * 16 + q4);
#pragma unroll
      for (int p = 0; p < 2; ++p) {
        int fc = nb * 128 + (wc * 2 + p) * 16 + fr;
#pragma unroll
        for (int i = 0; i < 4; ++i) {
          float gv = acc[mi][2 * p][i];
          float hv = gv / (1.f + __expf(-gv)) * acc[mi][2 * p + 1][i];
          hb[(rbase + i) * (size_t)F_ + fc] = (_Float16)hv;
        }
      }
    }
  } else {
    float* yb = (float*)(ks == 0 ? outp : outp2);
#pragma unroll
    for (int mi = 0; mi < MROW; ++mi) {
      size_t rbase = (size_t)(row0 + wr * 128 + mi * 16 + q4);
#pragma unroll
      for (int ni = 0; ni < 4; ++ni) {
        int col = nb * 256 + wc * 64 + ni * 16 + fr;
#pragma unroll
        for (int i = 0; i < 4; ++i)
          yb[(rbase + i) * (size_t)D_ + col] = acc[mi][ni][i];
      }
    }
  }
}

// ---------------- combine: out = g0*(y0a+y0b) + g1*(y1a+y1b) ----------------
__global__ __launch_bounds__(256) void combine_kernel(
    const float* __restrict__ ya, const float* __restrict__ yb2,
    const int* __restrict__ slot_of, const float* __restrict__ tok_g,
    float* __restrict__ out) {
  int t = blockIdx.x, i = threadIdx.x;
  int s0 = slot_of[t * 2], s1 = slot_of[t * 2 + 1];
  float g0 = tok_g[t * 2], g1 = tok_g[t * 2 + 1];
  float4 a0 = ((const float4*)(ya + (size_t)s0 * D_))[i];
  float4 a1 = ((const float4*)(yb2 + (size_t)s0 * D_))[i];
  float4 b0 = ((const float4*)(ya + (size_t)s1 * D_))[i];
  float4 b1 = ((const float4*)(yb2 + (size_t)s1 * D_))[i];
  float4 r;
  r.x = g0 * (a0.x + a1.x) + g1 * (b0.x + b1.x);
  r.y = g0 * (a0.y + a1.y) + g1 * (b0.y + b1.y);
  r.z = g0 * (a0.z + a1.z) + g1 * (b0.z + b1.z);
  r.w = g0 * (a0.w + a1.w) + g1 * (b0.w + b1.w);
  ((float4*)(out + (size_t)t * D_))[i] = r;
}

extern "C" void kernel_launch(void* const* d_in, const int* in_sizes, int n_in,
                              void* d_out, int out_size, void* d_ws, size_t ws_size,
                              hipStream_t stream) {
  const float* x  = (const float*)d_in[0];
  const float* rw = (const float*)d_in[1];
  const float* rbc = (const float*)d_in[2];
  const float* w1 = (const float*)d_in[3];
  const float* w2 = (const float*)d_in[4];  // dict order: w2 before w3
  const float* w3 = (const float*)d_in[5];
  float* out = (float*)d_out;

  char* ws = (char*)d_ws;
  size_t off = 0;
  auto take = [&](size_t bytes) {
    char* p = ws + off;
    off = (off + bytes + 255) & ~(size_t)255;
    return p;
  };
  _Float16* x16 = (_Float16*)take((size_t)NTOK * D_ * 2);
  _Float16* w13 = (_Float16*)take((size_t)E_ * 2 * F_ * D_ * 2);  // 128 MB
  _Float16* w2h = (_Float16*)take((size_t)E_ * D_ * F_ * 2);      // 64 MB
  _Float16* hbuf = (_Float16*)take((size_t)SLOT_CAP * F_ * 2);    // 151 MB
  float* ybuf = (float*)take((size_t)SLOT_CAP * D_ * 4);          // 75.5 MB
  int* slot_token = (int*)take((size_t)SLOT_CAP * 4);
  int* tok_e = (int*)take((size_t)NTOK * 2 * 4);
  float* tok_g = (float*)take((size_t)NTOK * 2 * 4);
  int* slot_of = (int*)take((size_t)NTOK * 2 * 4);
  int* counts = (int*)take(E_ * 4);
  int* cursor = (int*)take(E_ * 4);
  int* offs = (int*)take((E_ + 1) * 4);
  // split-K partial #1 reuses w13's space (dead after gemm1; stream-serialized)
  float* ybuf2 = (float*)w13;

  cvt_w13_kernel<<<4096, 256, 0, stream>>>(w1, w3, w13, E_ * F_ * D_ / 4);
  cvt_kernel<<<4096, 256, 0, stream>>>(w2, w2h, E_ * D_ * F_ / 4);
  init_kernel<<<(SLOT_CAP + 255) / 256, 256, 0, stream>>>(slot_token, counts, cursor);
  router_kernel<<<NTOK / 4, 256, 0, stream>>>(x, rw, rbc, x16, tok_e, tok_g, counts);
  scan_kernel<<<1, 64, 0, stream>>>(counts, offs);
  scatter_kernel<<<(NTOK * 2 + 255) / 256, 256, 0, stream>>>(tok_e, offs, cursor, slot_token, slot_of);
  // gemm1: 256x256, M<=18432 x Nvirt=8192 x K=1024 -> grid 8*9*32, ORD0 (share B)
  moe_gemm_kernel<0, 0, 1, 1024, 32, 9, 8192><<<2304, 512, 0, stream>>>(
      x16, w13, slot_token, offs, (void*)hbuf, nullptr);
  // gemm2: 256x256, split-K=2, M<=18432 x N=1024 x K=4096 -> grid 8*18*4, ORD1
  moe_gemm_kernel<1, 1, 2, 4096, 4, 18, 1024><<<576, 512, 0, stream>>>(
      hbuf, w2h, slot_token, offs, (void*)ybuf, (void*)ybuf2);
  combine_kernel<<<NTOK, 256, 0, stream>>>(ybuf, ybuf2, slot_of, tok_g, out);
}

// Round 9
// 895.219 us; speedup vs baseline: 1.0246x; 1.0061x over previous
//
#include <hip/hip_runtime.h>
#include <hip/hip_fp16.h>

// MoE top-2 SwiGLU, MI355X. Sparse grouped-GEMM, 256-aligned expert segments.
// Both GEMMs: 256x256 tile, 8 waves, 16x16x32 f16 MFMA, proven 0-conflict XOR
// swizzle (pre-swizzled global source), 4 LDS buffers, distance-3 gload prefetch.
// m201-ported inner schedule: per K=32 step, TWO phases, each
//   {ds_reads issued -> s_barrier -> lgkmcnt(0) -> setprio(1) 16xMFMA setprio(0) -> s_barrier}
// with 2 gloads staged per phase and ONE counted vmcnt(8) per step (tail 8/4/0).
// gemm1: virtual-N=8192 (w1/w3 interleaved 16-col) -> silu*mul -> h fp16. ORD0.
// gemm2: h @ w2^T, split-K=2 (partials ybuf + reused-w13), ORD1. combine: gated sum.

#define NTOK 8192
#define D_ 1024
#define F_ 4096
#define E_ 8
#define SLOT_CAP 18432  // 2*8192 + 8*256

using half8 = __attribute__((ext_vector_type(8))) _Float16;
using half4 = __attribute__((ext_vector_type(4))) _Float16;
using f32x4 = __attribute__((ext_vector_type(4))) float;

__device__ __forceinline__ void gload16(const void* g, void* l) {
  __builtin_amdgcn_global_load_lds((const __attribute__((address_space(1))) void*)g,
                                   (__attribute__((address_space(3))) void*)l, 16, 0, 0);
}

// ---------------- fp32 -> fp16 convert ----------------
__global__ __launch_bounds__(256) void cvt_kernel(const float* __restrict__ src,
                                                  _Float16* __restrict__ dst, int n4) {
  int i = blockIdx.x * 256 + threadIdx.x;
  int stride = gridDim.x * 256;
  for (; i < n4; i += stride) {
    float4 v = ((const float4*)src)[i];
    half4 h;
    h.x = (_Float16)v.x; h.y = (_Float16)v.y; h.z = (_Float16)v.z; h.w = (_Float16)v.w;
    ((half4*)dst)[i] = h;
  }
}

// w1,w3 -> interleaved virtual rows w13[e][8192][1024]:
// vrow = ((f>>4)<<5) | (sel<<4) | (f&15); sel 0=w1(gate), 1=w3(up).
__global__ __launch_bounds__(256) void cvt_w13_kernel(const float* __restrict__ w1,
                                                      const float* __restrict__ w3,
                                                      _Float16* __restrict__ w13, int n4) {
  int i = blockIdx.x * 256 + threadIdx.x;
  int stride = gridDim.x * 256;
  for (; i < n4; i += stride) {
    int d4 = i & 255;   // D/4 = 256
    int row = i >> 8;   // e*4096 + f
    int e = row >> 12, f = row & 4095;
    size_t vbase = ((size_t)e << 13) | ((size_t)(f >> 4) << 5) | (size_t)(f & 15);
    float4 v1 = ((const float4*)w1)[i];
    float4 v3 = ((const float4*)w3)[i];
    half4 h1, h3;
    h1.x = (_Float16)v1.x; h1.y = (_Float16)v1.y; h1.z = (_Float16)v1.z; h1.w = (_Float16)v1.w;
    h3.x = (_Float16)v3.x; h3.y = (_Float16)v3.y; h3.z = (_Float16)v3.z; h3.w = (_Float16)v3.w;
    ((half4*)w13)[vbase * 256 + d4] = h1;
    ((half4*)w13)[(vbase + 16) * 256 + d4] = h3;
  }
}

// ---------------- router (+ fused x fp32->fp16) ----------------
__global__ __launch_bounds__(256) void router_kernel(
    const float* __restrict__ x, const float* __restrict__ rw, const float* __restrict__ rbias,
    _Float16* __restrict__ x16, int* __restrict__ tok_e, float* __restrict__ tok_g,
    int* __restrict__ counts) {
  int wv = threadIdx.x >> 6, lane = threadIdx.x & 63;
  int t = blockIdx.x * 4 + wv;
  const float4* xr = (const float4*)(x + (size_t)t * D_);
  float acc[E_];
#pragma unroll
  for (int e = 0; e < E_; ++e) acc[e] = 0.f;
  for (int i = lane; i < D_ / 4; i += 64) {
    float4 xv = xr[i];
    half4 hx;
    hx.x = (_Float16)xv.x; hx.y = (_Float16)xv.y; hx.z = (_Float16)xv.z; hx.w = (_Float16)xv.w;
    ((half4*)(x16 + (size_t)t * D_))[i] = hx;
#pragma unroll
    for (int e = 0; e < E_; ++e) {
      float4 wv4 = ((const float4*)(rw + (size_t)e * D_))[i];
      acc[e] += xv.x * wv4.x + xv.y * wv4.y + xv.z * wv4.z + xv.w * wv4.w;
    }
  }
#pragma unroll
  for (int e = 0; e < E_; ++e) {
#pragma unroll
    for (int off = 32; off > 0; off >>= 1) acc[e] += __shfl_down(acc[e], off);
  }
  if (lane == 0) {
    float p[E_], mx = -1e30f;
#pragma unroll
    for (int e = 0; e < E_; ++e) { p[e] = acc[e] + rbias[e]; mx = fmaxf(mx, p[e]); }
#pragma unroll
    for (int e = 0; e < E_; ++e) p[e] = expf(p[e] - mx);
    int i0 = 0;
#pragma unroll
    for (int e = 1; e < E_; ++e) if (p[e] > p[i0]) i0 = e;
    int i1 = (i0 == 0) ? 1 : 0;
#pragma unroll
    for (int e = 0; e < E_; ++e) if (e != i0 && p[e] > p[i1]) i1 = e;
    float s = p[i0] + p[i1];
    tok_e[t * 2] = i0; tok_e[t * 2 + 1] = i1;
    tok_g[t * 2] = p[i0] / s; tok_g[t * 2 + 1] = p[i1] / s;
    atomicAdd(&counts[i0], 1); atomicAdd(&counts[i1], 1);
  }
}

__global__ void init_kernel(int* slot_token, int* counts, int* cursor) {
  int i = blockIdx.x * 256 + threadIdx.x;
  if (blockIdx.x == 0 && threadIdx.x < E_) { counts[threadIdx.x] = 0; cursor[threadIdx.x] = 0; }
  if (i < SLOT_CAP) slot_token[i] = 0;  // padding -> token 0 (never combined)
}

__global__ void scan_kernel(const int* __restrict__ counts, int* __restrict__ offs) {
  if (threadIdx.x == 0) {
    int o = 0;
    for (int e = 0; e < E_; ++e) { offs[e] = o; o += ((counts[e] + 255) / 256) * 256; }
    offs[E_] = o;
  }
}

__global__ void scatter_kernel(const int* __restrict__ tok_e, const int* __restrict__ offs,
                               int* __restrict__ cursor, int* __restrict__ slot_token,
                               int* __restrict__ slot_of) {
  int i = blockIdx.x * 256 + threadIdx.x;
  if (i >= NTOK * 2) return;
  int e = tok_e[i];
  int pos = offs[e] + atomicAdd(&cursor[e], 1);
  slot_token[pos] = i >> 1;
  slot_of[i] = pos;
}

// ---------------- pipelined grouped GEMM (16x16x32 f16, BM=256, BN=256) ----------------
template <int MODE, int ORD, int KSPLIT, int KD, int NBN, int RPX, int BEROWS>
__global__ __launch_bounds__(512, 2) void moe_gemm_kernel(
    const _Float16* __restrict__ Amat, const _Float16* __restrict__ Bmat,
    const int* __restrict__ slot_token, const int* __restrict__ offs,
    void* __restrict__ outp, void* __restrict__ outp2) {
  constexpr int BM = 256;
  constexpr int MROW = 8;               // 16-row m-frags per wave
  constexpr int AH = BM * 32;           // A halves per buffer (8192)
  constexpr int BUFH = (BM + 256) * 32; // 16384 halves = 32 KB
  constexpr int KL = KD / KSPLIT;       // K span per block
  constexpr int NT = KL / 32;           // K-steps (multiple of 4, >= 8)
  __shared__ _Float16 lds[4 * BUFH];    // 128 KB

  int id = blockIdx.x;
  int xcd = id & 7, idx = id >> 3;  // grid = 8 * RPX * NBN
  int vr, nb;
  if constexpr (ORD == 0) {
    int band = idx / (8 * NBN);
    int i2 = idx - band * (8 * NBN);
    int rib = (RPX - band * 8) < 8 ? (RPX - band * 8) : 8;
    nb = i2 / rib;
    vr = xcd * RPX + band * 8 + (i2 - nb * rib);
  } else {
    nb = idx % NBN;
    vr = xcd * RPX + idx / NBN;
  }
  int rb = vr, ks = 0;
  if constexpr (KSPLIT == 2) { rb = vr >> 1; ks = vr & 1; }
  int row0 = rb * BM;
  if (row0 >= offs[E_]) return;
  int e = 0;
#pragma unroll
  for (int i = 1; i < E_; ++i) if (row0 >= offs[i]) e = i;
  int koff = ks * KL;

  int t = threadIdx.x, l = t & 63, w = t >> 6;
  int wr = w >> 2, wc = w & 3;
  int srow = t >> 2;                           // 0..127 staging row
  int gsrc8 = ((l & 3) ^ ((l >> 3) & 3)) * 8;  // pre-swizzled source k-granule

  const _Float16* aP0;
  const _Float16* aP1;
  if constexpr (MODE == 0) {
    int tk0 = slot_token[row0 + srow];
    int tk1 = slot_token[row0 + srow + 128];
    aP0 = Amat + (size_t)tk0 * KD + koff + gsrc8;
    aP1 = Amat + (size_t)tk1 * KD + koff + gsrc8;
  } else {
    aP0 = Amat + (size_t)(row0 + srow) * KD + koff + gsrc8;
    aP1 = Amat + (size_t)(row0 + srow + 128) * KD + koff + gsrc8;
  }
  const _Float16* b0P =
      Bmat + ((size_t)e * BEROWS + (size_t)nb * 256 + srow) * KD + koff + gsrc8;
  const _Float16* b1P = b0P + (size_t)128 * KD;

  // proven 0-conflict read pattern: 16-row frags, granule kg = l>>4
  int fr = l & 15, kg = l >> 4;
  int swz8 = (kg ^ ((fr >> 1) & 3)) * 8;
  const int rA = (wr * 128 + fr) * 32 + swz8;
  const int rB = AH + (wc * 64 + fr) * 32 + swz8;

  half8 aF[4];
  half8 bF[4];
  f32x4 acc[MROW][4];
#pragma unroll
  for (int m = 0; m < MROW; ++m)
#pragma unroll
    for (int n = 0; n < 4; ++n) acc[m][n] = (f32x4){0.f, 0.f, 0.f, 0.f};

  // prologue: stage tiles 0,1,2 into buf0..2; wait tile 0 (tiles 1,2 in flight)
#pragma unroll
  for (int tt = 0; tt < 3; ++tt) {
    gload16(aP0 + tt * 32, &lds[tt * BUFH + w * 512]);
    gload16(aP1 + tt * 32, &lds[tt * BUFH + 4096 + w * 512]);
    gload16(b0P + tt * 32, &lds[tt * BUFH + AH + w * 512]);
    gload16(b1P + tt * 32, &lds[tt * BUFH + AH + 4096 + w * 512]);
  }
  asm volatile("s_waitcnt vmcnt(8)" ::: "memory");
  __builtin_amdgcn_s_barrier();
  __builtin_amdgcn_sched_barrier(0);
  // advance source pointers to tile 3 (first in-loop staged tile)
  aP0 += 96; aP1 += 96; b0P += 96; b1P += 96;

#define MF16(BASE)                                                           \
  _Pragma("unroll") for (int mi = 0; mi < 4; ++mi)                           \
  _Pragma("unroll") for (int ni = 0; ni < 4; ++ni)                           \
      acc[(BASE) + mi][ni] = __builtin_amdgcn_mfma_f32_16x16x32_f16(         \
          aF[mi], bF[ni], acc[(BASE) + mi][ni], 0, 0, 0);

// One K=32 step = 2 m201-style phases. Reads issued pre-barrier; lgkmcnt(0)
// post-barrier -> DS-pipe drain overlaps other waves' MFMA region.
#define STEPP(U, PRE, WN)                                                         \
  {                                                                               \
    constexpr int bi_ = (U) & 3;                                                  \
    constexpr int bs_ = ((U) + 3) & 3;                                            \
    const _Float16* cb_ = &lds[bi_ * BUFH];                                       \
    if (PRE) {                                                                    \
      gload16(aP0 + (U) * 32, &lds[bs_ * BUFH + w * 512]);                        \
      gload16(aP1 + (U) * 32, &lds[bs_ * BUFH + 4096 + w * 512]);                 \
    }                                                                             \
    aF[0] = *(const half8*)(cb_ + rA);                                            \
    aF[1] = *(const half8*)(cb_ + rA + 512);                                      \
    aF[2] = *(const half8*)(cb_ + rA + 1024);                                     \
    aF[3] = *(const half8*)(cb_ + rA + 1536);                                     \
    bF[0] = *(const half8*)(cb_ + rB);                                            \
    bF[1] = *(const half8*)(cb_ + rB + 512);                                      \
    bF[2] = *(const half8*)(cb_ + rB + 1024);                                     \
    bF[3] = *(const half8*)(cb_ + rB + 1536);                                     \
    __builtin_amdgcn_sched_barrier(0);                                            \
    __builtin_amdgcn_s_barrier();                                                 \
    asm volatile("s_waitcnt lgkmcnt(0)" ::: "memory");                            \
    __builtin_amdgcn_sched_barrier(0);                                            \
    __builtin_amdgcn_s_setprio(1);                                                \
    MF16(0)                                                                       \
    __builtin_amdgcn_s_setprio(0);                                                \
    __builtin_amdgcn_sched_barrier(0);                                            \
    __builtin_amdgcn_s_barrier();                                                 \
    if (PRE) {                                                                    \
      gload16(b0P + (U) * 32, &lds[bs_ * BUFH + AH + w * 512]);                   \
      gload16(b1P + (U) * 32, &lds[bs_ * BUFH + AH + 4096 + w * 512]);            \
    }                                                                             \
    aF[0] = *(const half8*)(cb_ + rA + 2048);                                     \
    aF[1] = *(const half8*)(cb_ + rA + 2560);                                     \
    aF[2] = *(const half8*)(cb_ + rA + 3072);                                     \
    aF[3] = *(const half8*)(cb_ + rA + 3584);                                     \
    __builtin_amdgcn_sched_barrier(0);                                            \
    __builtin_amdgcn_s_barrier();                                                 \
    asm volatile("s_waitcnt lgkmcnt(0)" ::: "memory");                            \
    __builtin_amdgcn_sched_barrier(0);                                            \
    __builtin_amdgcn_s_setprio(1);                                                \
    MF16(4)                                                                       \
    __builtin_amdgcn_s_setprio(0);                                                \
    if ((WN) >= 0) {                                                              \
      asm volatile("s_waitcnt vmcnt(%0)" ::"i"((WN) >= 0 ? (WN) : 0) : "memory"); \
      __builtin_amdgcn_sched_barrier(0);                                          \
      __builtin_amdgcn_s_barrier();                                               \
      __builtin_amdgcn_sched_barrier(0);                                          \
    }                                                                             \
  }

  for (int j4 = 0; j4 < NT - 4; j4 += 4) {
    STEPP(0, true, 8)
    STEPP(1, true, 8)
    STEPP(2, true, 8)
    STEPP(3, true, 8)
    aP0 += 128; aP1 += 128; b0P += 128; b1P += 128;
  }
  // tail: steps NT-4 .. NT-1
  STEPP(0, true, 8)    // stages tile NT-1; tile NT-3 resident after
  STEPP(1, false, 4)   // tile NT-2 resident after
  STEPP(2, false, 0)   // tile NT-1 resident after
  STEPP(3, false, -1)  // last step, no trailing sync
#undef STEPP
#undef MF16

  // epilogue. C/D 16x16: col = lane&15, row = (lane>>4)*4 + i  [m89 verified]
  int q4 = kg * 4;
  if constexpr (MODE == 0) {
    _Float16* hb = (_Float16*)outp;
#pragma unroll
    for (int mi = 0; mi < MROW; ++mi) {
      size_t rbase = (size_t)(row0 + wr * 128 + mi * 16 + q4);
#pragma unroll
      for (int p = 0; p < 2; ++p) {
        int fc = nb * 128 + (wc * 2 + p) * 16 + fr;
#pragma unroll
        for (int i = 0; i < 4; ++i) {
          float gv = acc[mi][2 * p][i];
          float hv = gv / (1.f + __expf(-gv)) * acc[mi][2 * p + 1][i];
          hb[(rbase + i) * (size_t)F_ + fc] = (_Float16)hv;
        }
      }
    }
  } else {
    float* yb = (float*)(ks == 0 ? outp : outp2);
#pragma unroll
    for (int mi = 0; mi < MROW; ++mi) {
      size_t rbase = (size_t)(row0 + wr * 128 + mi * 16 + q4);
#pragma unroll
      for (int ni = 0; ni < 4; ++ni) {
        int col = nb * 256 + wc * 64 + ni * 16 + fr;
#pragma unroll
        for (int i = 0; i < 4; ++i)
          yb[(rbase + i) * (size_t)D_ + col] = acc[mi][ni][i];
      }
    }
  }
}

// ---------------- combine: out = g0*(y0a+y0b) + g1*(y1a+y1b) ----------------
__global__ __launch_bounds__(256) void combine_kernel(
    const float* __restrict__ ya, const float* __restrict__ yb2,
    const int* __restrict__ slot_of, const float* __restrict__ tok_g,
    float* __restrict__ out) {
  int t = blockIdx.x, i = threadIdx.x;
  int s0 = slot_of[t * 2], s1 = slot_of[t * 2 + 1];
  float g0 = tok_g[t * 2], g1 = tok_g[t * 2 + 1];
  float4 a0 = ((const float4*)(ya + (size_t)s0 * D_))[i];
  float4 a1 = ((const float4*)(yb2 + (size_t)s0 * D_))[i];
  float4 b0 = ((const float4*)(ya + (size_t)s1 * D_))[i];
  float4 b1 = ((const float4*)(yb2 + (size_t)s1 * D_))[i];
  float4 r;
  r.x = g0 * (a0.x + a1.x) + g1 * (b0.x + b1.x);
  r.y = g0 * (a0.y + a1.y) + g1 * (b0.y + b1.y);
  r.z = g0 * (a0.z + a1.z) + g1 * (b0.z + b1.z);
  r.w = g0 * (a0.w + a1.w) + g1 * (b0.w + b1.w);
  ((float4*)(out + (size_t)t * D_))[i] = r;
}

extern "C" void kernel_launch(void* const* d_in, const int* in_sizes, int n_in,
                              void* d_out, int out_size, void* d_ws, size_t ws_size,
                              hipStream_t stream) {
  const float* x  = (const float*)d_in[0];
  const float* rw = (const float*)d_in[1];
  const float* rbc = (const float*)d_in[2];
  const float* w1 = (const float*)d_in[3];
  const float* w2 = (const float*)d_in[4];  // dict order: w2 before w3
  const float* w3 = (const float*)d_in[5];
  float* out = (float*)d_out;

  char* ws = (char*)d_ws;
  size_t off = 0;
  auto take = [&](size_t bytes) {
    char* p = ws + off;
    off = (off + bytes + 255) & ~(size_t)255;
    return p;
  };
  _Float16* x16 = (_Float16*)take((size_t)NTOK * D_ * 2);
  _Float16* w13 = (_Float16*)take((size_t)E_ * 2 * F_ * D_ * 2);  // 128 MB
  _Float16* w2h = (_Float16*)take((size_t)E_ * D_ * F_ * 2);      // 64 MB
  _Float16* hbuf = (_Float16*)take((size_t)SLOT_CAP * F_ * 2);    // 151 MB
  float* ybuf = (float*)take((size_t)SLOT_CAP * D_ * 4);          // 75.5 MB
  int* slot_token = (int*)take((size_t)SLOT_CAP * 4);
  int* tok_e = (int*)take((size_t)NTOK * 2 * 4);
  float* tok_g = (float*)take((size_t)NTOK * 2 * 4);
  int* slot_of = (int*)take((size_t)NTOK * 2 * 4);
  int* counts = (int*)take(E_ * 4);
  int* cursor = (int*)take(E_ * 4);
  int* offs = (int*)take((E_ + 1) * 4);
  // split-K partial #1 reuses w13's space (dead after gemm1; stream-serialized)
  float* ybuf2 = (float*)w13;

  cvt_w13_kernel<<<4096, 256, 0, stream>>>(w1, w3, w13, E_ * F_ * D_ / 4);
  cvt_kernel<<<4096, 256, 0, stream>>>(w2, w2h, E_ * D_ * F_ / 4);
  init_kernel<<<(SLOT_CAP + 255) / 256, 256, 0, stream>>>(slot_token, counts, cursor);
  router_kernel<<<NTOK / 4, 256, 0, stream>>>(x, rw, rbc, x16, tok_e, tok_g, counts);
  scan_kernel<<<1, 64, 0, stream>>>(counts, offs);
  scatter_kernel<<<(NTOK * 2 + 255) / 256, 256, 0, stream>>>(tok_e, offs, cursor, slot_token, slot_of);
  // gemm1: 256x256, M<=18432 x Nvirt=8192 x K=1024 -> grid 8*9*32, ORD0 (share B)
  moe_gemm_kernel<0, 0, 1, 1024, 32, 9, 8192><<<2304, 512, 0, stream>>>(
      x16, w13, slot_token, offs, (void*)hbuf, nullptr);
  // gemm2: 256x256, split-K=2, M<=18432 x N=1024 x K=4096 -> grid 8*18*4, ORD1
  moe_gemm_kernel<1, 1, 2, 4096, 4, 18, 1024><<<576, 512, 0, stream>>>(
      hbuf, w2h, slot_token, offs, (void*)ybuf, (void*)ybuf2);
  combine_kernel<<<NTOK, 256, 0, stream>>>(ybuf, ybuf2, slot_of, tok_g, out);
}

// Round 10
// 737.365 us; speedup vs baseline: 1.2439x; 1.2141x over previous
//
#include <hip/hip_runtime.h>
#include <hip/hip_fp16.h>

// MoE top-2 SwiGLU, MI355X. Sparse grouped-GEMM, 256-aligned expert segments.
// GEMMs (R9-proven, unchanged): 256x256 tile, 8 waves, 16x16x32 f16 MFMA,
// 0-conflict XOR swizzle, 4 LDS buffers, distance-3 gload prefetch, 2-phase
// m201-style inner schedule, counted vmcnt per K-step.
// NEW: atomic-free single-block ballot-scan scatter (deterministic), router
// without atomics, fused weight-convert kernel. 6 launches total.
// gemm1: virtual-N=8192 (w1/w3 interleaved 16-col) -> silu*mul -> h fp16. ORD0.
// gemm2: h @ w2^T, split-K=2 (partials ybuf + reused-w13), ORD1. combine: gated sum.

#define NTOK 8192
#define D_ 1024
#define F_ 4096
#define E_ 8
#define SLOT_CAP 18432  // 2*8192 + 8*256

using half8 = __attribute__((ext_vector_type(8))) _Float16;
using half4 = __attribute__((ext_vector_type(4))) _Float16;
using f32x4 = __attribute__((ext_vector_type(4))) float;

__device__ __forceinline__ void gload16(const void* g, void* l) {
  __builtin_amdgcn_global_load_lds((const __attribute__((address_space(1))) void*)g,
                                   (__attribute__((address_space(3))) void*)l, 16, 0, 0);
}

// ---------------- fused weight convert: w1,w3 -> w13 interleave; w2 -> fp16 ----------------
// w13[e][8192][1024]: vrow = ((f>>4)<<5) | (sel<<4) | (f&15); sel 0=w1(gate), 1=w3(up).
__global__ __launch_bounds__(256) void cvt_weights_kernel(
    const float* __restrict__ w1, const float* __restrict__ w3, const float* __restrict__ w2,
    _Float16* __restrict__ w13, _Float16* __restrict__ w2h) {
  int b = blockIdx.x;
  if (b < 4096) {
    for (int i = b * 256 + threadIdx.x; i < E_ * F_ * D_ / 4; i += 4096 * 256) {
      int d4 = i & 255;   // D/4 = 256
      int row = i >> 8;   // e*4096 + f
      int e = row >> 12, f = row & 4095;
      size_t vbase = ((size_t)e << 13) | ((size_t)(f >> 4) << 5) | (size_t)(f & 15);
      float4 v1 = ((const float4*)w1)[i];
      float4 v3 = ((const float4*)w3)[i];
      half4 h1, h3;
      h1.x = (_Float16)v1.x; h1.y = (_Float16)v1.y; h1.z = (_Float16)v1.z; h1.w = (_Float16)v1.w;
      h3.x = (_Float16)v3.x; h3.y = (_Float16)v3.y; h3.z = (_Float16)v3.z; h3.w = (_Float16)v3.w;
      ((half4*)w13)[vbase * 256 + d4] = h1;
      ((half4*)w13)[(vbase + 16) * 256 + d4] = h3;
    }
  } else {
    for (int i = (b - 4096) * 256 + threadIdx.x; i < E_ * D_ * F_ / 4; i += 4096 * 256) {
      float4 v = ((const float4*)w2)[i];
      half4 h;
      h.x = (_Float16)v.x; h.y = (_Float16)v.y; h.z = (_Float16)v.z; h.w = (_Float16)v.w;
      ((half4*)w2h)[i] = h;
    }
  }
}

// ---------------- router (+ fused x fp32->fp16), NO atomics ----------------
__global__ __launch_bounds__(256) void router_kernel(
    const float* __restrict__ x, const float* __restrict__ rw, const float* __restrict__ rbias,
    _Float16* __restrict__ x16, int* __restrict__ tok_e, float* __restrict__ tok_g) {
  int wv = threadIdx.x >> 6, lane = threadIdx.x & 63;
  int t = blockIdx.x * 4 + wv;
  const float4* xr = (const float4*)(x + (size_t)t * D_);
  float acc[E_];
#pragma unroll
  for (int e = 0; e < E_; ++e) acc[e] = 0.f;
  for (int i = lane; i < D_ / 4; i += 64) {
    float4 xv = xr[i];
    half4 hx;
    hx.x = (_Float16)xv.x; hx.y = (_Float16)xv.y; hx.z = (_Float16)xv.z; hx.w = (_Float16)xv.w;
    ((half4*)(x16 + (size_t)t * D_))[i] = hx;
#pragma unroll
    for (int e = 0; e < E_; ++e) {
      float4 wv4 = ((const float4*)(rw + (size_t)e * D_))[i];
      acc[e] += xv.x * wv4.x + xv.y * wv4.y + xv.z * wv4.z + xv.w * wv4.w;
    }
  }
#pragma unroll
  for (int e = 0; e < E_; ++e) {
#pragma unroll
    for (int off = 32; off > 0; off >>= 1) acc[e] += __shfl_down(acc[e], off);
  }
  if (lane == 0) {
    float p[E_], mx = -1e30f;
#pragma unroll
    for (int e = 0; e < E_; ++e) { p[e] = acc[e] + rbias[e]; mx = fmaxf(mx, p[e]); }
#pragma unroll
    for (int e = 0; e < E_; ++e) p[e] = expf(p[e] - mx);
    int i0 = 0;
#pragma unroll
    for (int e = 1; e < E_; ++e) if (p[e] > p[i0]) i0 = e;
    int i1 = (i0 == 0) ? 1 : 0;
#pragma unroll
    for (int e = 0; e < E_; ++e) if (e != i0 && p[e] > p[i1]) i1 = e;
    float s = p[i0] + p[i1];
    tok_e[t * 2] = i0; tok_e[t * 2 + 1] = i1;
    tok_g[t * 2] = p[i0] / s; tok_g[t * 2 + 1] = p[i1] / s;
  }
}

// ---------------- atomic-free ordered scatter (single block, 1024 thr) ----------------
// Pass 1: ballot histogram -> totals -> offs (+ fill padding slots with token 0).
// Pass 2: order-preserving rank (ballot popc + wave prefix) -> slot assignment.
__global__ __launch_bounds__(1024) void scatter_kernel(
    const int* __restrict__ tok_e, int* __restrict__ slot_token,
    int* __restrict__ slot_of, int* __restrict__ offs) {
  __shared__ int wcnt[16][E_];
  int t = threadIdx.x, lane = t & 63, wv = t >> 6;

  int total[E_];
#pragma unroll
  for (int e = 0; e < E_; ++e) total[e] = 0;
  for (int c = 0; c < NTOK * 2; c += 1024) {
    int ei = tok_e[c + t];
#pragma unroll
    for (int e = 0; e < E_; ++e) {
      unsigned long long m = __ballot(ei == e);
      if (lane == 0) wcnt[wv][e] = __popcll(m);
    }
    __syncthreads();
#pragma unroll
    for (int e = 0; e < E_; ++e) {
      int s = 0;
#pragma unroll
      for (int w2 = 0; w2 < 16; ++w2) s += wcnt[w2][e];
      total[e] += s;
    }
    __syncthreads();
  }
  int base[E_ + 1];
  {
    int o = 0;
#pragma unroll
    for (int e = 0; e < E_; ++e) { base[e] = o; o += ((total[e] + 255) >> 8) << 8; }
    base[E_] = o;
  }
  if (t <= E_) offs[t] = base[t];
  // padding slots -> token 0 (finite garbage, never combined)
#pragma unroll
  for (int e = 0; e < E_; ++e)
    for (int p = base[e] + total[e] + t; p < base[e + 1]; p += 1024) slot_token[p] = 0;

  int run[E_];
#pragma unroll
  for (int e = 0; e < E_; ++e) run[e] = 0;
  for (int c = 0; c < NTOK * 2; c += 1024) {
    int ei = tok_e[c + t];
    int rank = 0;
#pragma unroll
    for (int e = 0; e < E_; ++e) {
      unsigned long long m = __ballot(ei == e);
      if (lane == 0) wcnt[wv][e] = __popcll(m);
      if (ei == e) rank = __popcll(m & ((1ULL << lane) - 1ULL));
    }
    __syncthreads();
    int mybase = 0, wbase = 0;
    int tot[E_];
#pragma unroll
    for (int e = 0; e < E_; ++e) {
      int s = 0;
#pragma unroll
      for (int w2 = 0; w2 < 16; ++w2) {
        int v = wcnt[w2][e];
        if (e == ei && w2 < wv) wbase += v;
        s += v;
      }
      tot[e] = s;
      if (e == ei) mybase = base[e] + run[e];
    }
    int pos = mybase + wbase + rank;
    slot_token[pos] = (c + t) >> 1;
    slot_of[c + t] = pos;
#pragma unroll
    for (int e = 0; e < E_; ++e) run[e] += tot[e];
    __syncthreads();
  }
}

// ---------------- pipelined grouped GEMM (16x16x32 f16, BM=256, BN=256) ----------------
template <int MODE, int ORD, int KSPLIT, int KD, int NBN, int RPX, int BEROWS>
__global__ __launch_bounds__(512, 2) void moe_gemm_kernel(
    const _Float16* __restrict__ Amat, const _Float16* __restrict__ Bmat,
    const int* __restrict__ slot_token, const int* __restrict__ offs,
    void* __restrict__ outp, void* __restrict__ outp2) {
  constexpr int BM = 256;
  constexpr int MROW = 8;               // 16-row m-frags per wave
  constexpr int AH = BM * 32;           // A halves per buffer (8192)
  constexpr int BUFH = (BM + 256) * 32; // 16384 halves = 32 KB
  constexpr int KL = KD / KSPLIT;       // K span per block
  constexpr int NT = KL / 32;           // K-steps (multiple of 4, >= 8)
  __shared__ _Float16 lds[4 * BUFH];    // 128 KB

  int id = blockIdx.x;
  int xcd = id & 7, idx = id >> 3;  // grid = 8 * RPX * NBN
  int vr, nb;
  if constexpr (ORD == 0) {
    int band = idx / (8 * NBN);
    int i2 = idx - band * (8 * NBN);
    int rib = (RPX - band * 8) < 8 ? (RPX - band * 8) : 8;
    nb = i2 / rib;
    vr = xcd * RPX + band * 8 + (i2 - nb * rib);
  } else {
    nb = idx % NBN;
    vr = xcd * RPX + idx / NBN;
  }
  int rb = vr, ks = 0;
  if constexpr (KSPLIT == 2) { rb = vr >> 1; ks = vr & 1; }
  int row0 = rb * BM;
  if (row0 >= offs[E_]) return;
  int e = 0;
#pragma unroll
  for (int i = 1; i < E_; ++i) if (row0 >= offs[i]) e = i;
  int koff = ks * KL;

  int t = threadIdx.x, l = t & 63, w = t >> 6;
  int wr = w >> 2, wc = w & 3;
  int srow = t >> 2;                           // 0..127 staging row
  int gsrc8 = ((l & 3) ^ ((l >> 3) & 3)) * 8;  // pre-swizzled source k-granule

  const _Float16* aP0;
  const _Float16* aP1;
  if constexpr (MODE == 0) {
    int tk0 = slot_token[row0 + srow];
    int tk1 = slot_token[row0 + srow + 128];
    aP0 = Amat + (size_t)tk0 * KD + koff + gsrc8;
    aP1 = Amat + (size_t)tk1 * KD + koff + gsrc8;
  } else {
    aP0 = Amat + (size_t)(row0 + srow) * KD + koff + gsrc8;
    aP1 = Amat + (size_t)(row0 + srow + 128) * KD + koff + gsrc8;
  }
  const _Float16* b0P =
      Bmat + ((size_t)e * BEROWS + (size_t)nb * 256 + srow) * KD + koff + gsrc8;
  const _Float16* b1P = b0P + (size_t)128 * KD;

  // proven 0-conflict read pattern: 16-row frags, granule kg = l>>4
  int fr = l & 15, kg = l >> 4;
  int swz8 = (kg ^ ((fr >> 1) & 3)) * 8;
  const int rA = (wr * 128 + fr) * 32 + swz8;
  const int rB = AH + (wc * 64 + fr) * 32 + swz8;

  half8 aF[4];
  half8 bF[4];
  f32x4 acc[MROW][4];
#pragma unroll
  for (int m = 0; m < MROW; ++m)
#pragma unroll
    for (int n = 0; n < 4; ++n) acc[m][n] = (f32x4){0.f, 0.f, 0.f, 0.f};

  // prologue: stage tiles 0,1,2 into buf0..2; wait tile 0 (tiles 1,2 in flight)
#pragma unroll
  for (int tt = 0; tt < 3; ++tt) {
    gload16(aP0 + tt * 32, &lds[tt * BUFH + w * 512]);
    gload16(aP1 + tt * 32, &lds[tt * BUFH + 4096 + w * 512]);
    gload16(b0P + tt * 32, &lds[tt * BUFH + AH + w * 512]);
    gload16(b1P + tt * 32, &lds[tt * BUFH + AH + 4096 + w * 512]);
  }
  asm volatile("s_waitcnt vmcnt(8)" ::: "memory");
  __builtin_amdgcn_s_barrier();
  __builtin_amdgcn_sched_barrier(0);
  // advance source pointers to tile 3 (first in-loop staged tile)
  aP0 += 96; aP1 += 96; b0P += 96; b1P += 96;

#define MF16(BASE)                                                           \
  _Pragma("unroll") for (int mi = 0; mi < 4; ++mi)                           \
  _Pragma("unroll") for (int ni = 0; ni < 4; ++ni)                           \
      acc[(BASE) + mi][ni] = __builtin_amdgcn_mfma_f32_16x16x32_f16(         \
          aF[mi], bF[ni], acc[(BASE) + mi][ni], 0, 0, 0);

// One K=32 step = 2 m201-style phases. Reads issued pre-barrier; lgkmcnt(0)
// post-barrier -> DS-pipe drain overlaps other waves' MFMA region.
#define STEPP(U, PRE, WN)                                                         \
  {                                                                               \
    constexpr int bi_ = (U) & 3;                                                  \
    constexpr int bs_ = ((U) + 3) & 3;                                            \
    const _Float16* cb_ = &lds[bi_ * BUFH];                                       \
    if (PRE) {                                                                    \
      gload16(aP0 + (U) * 32, &lds[bs_ * BUFH + w * 512]);                        \
      gload16(aP1 + (U) * 32, &lds[bs_ * BUFH + 4096 + w * 512]);                 \
    }                                                                             \
    aF[0] = *(const half8*)(cb_ + rA);                                            \
    aF[1] = *(const half8*)(cb_ + rA + 512);                                      \
    aF[2] = *(const half8*)(cb_ + rA + 1024);                                     \
    aF[3] = *(const half8*)(cb_ + rA + 1536);                                     \
    bF[0] = *(const half8*)(cb_ + rB);                                            \
    bF[1] = *(const half8*)(cb_ + rB + 512);                                      \
    bF[2] = *(const half8*)(cb_ + rB + 1024);                                     \
    bF[3] = *(const half8*)(cb_ + rB + 1536);                                     \
    __builtin_amdgcn_sched_barrier(0);                                            \
    __builtin_amdgcn_s_barrier();                                                 \
    asm volatile("s_waitcnt lgkmcnt(0)" ::: "memory");                            \
    __builtin_amdgcn_sched_barrier(0);                                            \
    __builtin_amdgcn_s_setprio(1);                                                \
    MF16(0)                                                                       \
    __builtin_amdgcn_s_setprio(0);                                                \
    __builtin_amdgcn_sched_barrier(0);                                            \
    __builtin_amdgcn_s_barrier();                                                 \
    if (PRE) {                                                                    \
      gload16(b0P + (U) * 32, &lds[bs_ * BUFH + AH + w * 512]);                   \
      gload16(b1P + (U) * 32, &lds[bs_ * BUFH + AH + 4096 + w * 512]);            \
    }                                                                             \
    aF[0] = *(const half8*)(cb_ + rA + 2048);                                     \
    aF[1] = *(const half8*)(cb_ + rA + 2560);                                     \
    aF[2] = *(const half8*)(cb_ + rA + 3072);                                     \
    aF[3] = *(const half8*)(cb_ + rA + 3584);                                     \
    __builtin_amdgcn_sched_barrier(0);                                            \
    __builtin_amdgcn_s_barrier();                                                 \
    asm volatile("s_waitcnt lgkmcnt(0)" ::: "memory");                            \
    __builtin_amdgcn_sched_barrier(0);                                            \
    __builtin_amdgcn_s_setprio(1);                                                \
    MF16(4)                                                                       \
    __builtin_amdgcn_s_setprio(0);                                                \
    if ((WN) >= 0) {                                                              \
      asm volatile("s_waitcnt vmcnt(%0)" ::"i"((WN) >= 0 ? (WN) : 0) : "memory"); \
      __builtin_amdgcn_sched_barrier(0);                                          \
      __builtin_amdgcn_s_barrier();                                               \
      __builtin_amdgcn_sched_barrier(0);                                          \
    }                                                                             \
  }

  for (int j4 = 0; j4 < NT - 4; j4 += 4) {
    STEPP(0, true, 8)
    STEPP(1, true, 8)
    STEPP(2, true, 8)
    STEPP(3, true, 8)
    aP0 += 128; aP1 += 128; b0P += 128; b1P += 128;
  }
  // tail: steps NT-4 .. NT-1
  STEPP(0, true, 8)    // stages tile NT-1; tile NT-3 resident after
  STEPP(1, false, 4)   // tile NT-2 resident after
  STEPP(2, false, 0)   // tile NT-1 resident after
  STEPP(3, false, -1)  // last step, no trailing sync
#undef STEPP
#undef MF16

  // epilogue. C/D 16x16: col = lane&15, row = (lane>>4)*4 + i  [m89 verified]
  int q4 = kg * 4;
  if constexpr (MODE == 0) {
    _Float16* hb = (_Float16*)outp;
#pragma unroll
    for (int mi = 0; mi < MROW; ++mi) {
      size_t rbase = (size_t)(row0 + wr * 128 + mi * 16 + q4);
#pragma unroll
      for (int p = 0; p < 2; ++p) {
        int fc = nb * 128 + (wc * 2 + p) * 16 + fr;
#pragma unroll
        for (int i = 0; i < 4; ++i) {
          float gv = acc[mi][2 * p][i];
          float hv = gv / (1.f + __expf(-gv)) * acc[mi][2 * p + 1][i];
          hb[(rbase + i) * (size_t)F_ + fc] = (_Float16)hv;
        }
      }
    }
  } else {
    float* yb = (float*)(ks == 0 ? outp : outp2);
#pragma unroll
    for (int mi = 0; mi < MROW; ++mi) {
      size_t rbase = (size_t)(row0 + wr * 128 + mi * 16 + q4);
#pragma unroll
      for (int ni = 0; ni < 4; ++ni) {
        int col = nb * 256 + wc * 64 + ni * 16 + fr;
#pragma unroll
        for (int i = 0; i < 4; ++i)
          yb[(rbase + i) * (size_t)D_ + col] = acc[mi][ni][i];
      }
    }
  }
}

// ---------------- combine: out = g0*(y0a+y0b) + g1*(y1a+y1b) ----------------
__global__ __launch_bounds__(256) void combine_kernel(
    const float* __restrict__ ya, const float* __restrict__ yb2,
    const int* __restrict__ slot_of, const float* __restrict__ tok_g,
    float* __restrict__ out) {
  int t = blockIdx.x, i = threadIdx.x;
  int s0 = slot_of[t * 2], s1 = slot_of[t * 2 + 1];
  float g0 = tok_g[t * 2], g1 = tok_g[t * 2 + 1];
  float4 a0 = ((const float4*)(ya + (size_t)s0 * D_))[i];
  float4 a1 = ((const float4*)(yb2 + (size_t)s0 * D_))[i];
  float4 b0 = ((const float4*)(ya + (size_t)s1 * D_))[i];
  float4 b1 = ((const float4*)(yb2 + (size_t)s1 * D_))[i];
  float4 r;
  r.x = g0 * (a0.x + a1.x) + g1 * (b0.x + b1.x);
  r.y = g0 * (a0.y + a1.y) + g1 * (b0.y + b1.y);
  r.z = g0 * (a0.z + a1.z) + g1 * (b0.z + b1.z);
  r.w = g0 * (a0.w + a1.w) + g1 * (b0.w + b1.w);
  ((float4*)(out + (size_t)t * D_))[i] = r;
}

extern "C" void kernel_launch(void* const* d_in, const int* in_sizes, int n_in,
                              void* d_out, int out_size, void* d_ws, size_t ws_size,
                              hipStream_t stream) {
  const float* x  = (const float*)d_in[0];
  const float* rw = (const float*)d_in[1];
  const float* rbc = (const float*)d_in[2];
  const float* w1 = (const float*)d_in[3];
  const float* w2 = (const float*)d_in[4];  // dict order: w2 before w3
  const float* w3 = (const float*)d_in[5];
  float* out = (float*)d_out;

  char* ws = (char*)d_ws;
  size_t off = 0;
  auto take = [&](size_t bytes) {
    char* p = ws + off;
    off = (off + bytes + 255) & ~(size_t)255;
    return p;
  };
  _Float16* x16 = (_Float16*)take((size_t)NTOK * D_ * 2);
  _Float16* w13 = (_Float16*)take((size_t)E_ * 2 * F_ * D_ * 2);  // 128 MB
  _Float16* w2h = (_Float16*)take((size_t)E_ * D_ * F_ * 2);      // 64 MB
  _Float16* hbuf = (_Float16*)take((size_t)SLOT_CAP * F_ * 2);    // 151 MB
  float* ybuf = (float*)take((size_t)SLOT_CAP * D_ * 4);          // 75.5 MB
  int* slot_token = (int*)take((size_t)SLOT_CAP * 4);
  int* tok_e = (int*)take((size_t)NTOK * 2 * 4);
  float* tok_g = (float*)take((size_t)NTOK * 2 * 4);
  int* slot_of = (int*)take((size_t)NTOK * 2 * 4);
  int* offs = (int*)take((E_ + 1) * 4);
  // split-K partial #1 reuses w13's space (dead after gemm1; stream-serialized)
  float* ybuf2 = (float*)w13;

  cvt_weights_kernel<<<8192, 256, 0, stream>>>(w1, w3, w2, w13, w2h);
  router_kernel<<<NTOK / 4, 256, 0, stream>>>(x, rw, rbc, x16, tok_e, tok_g);
  scatter_kernel<<<1, 1024, 0, stream>>>(tok_e, slot_token, slot_of, offs);
  // gemm1: 256x256, M<=18432 x Nvirt=8192 x K=1024 -> grid 8*9*32, ORD0 (share B)
  moe_gemm_kernel<0, 0, 1, 1024, 32, 9, 8192><<<2304, 512, 0, stream>>>(
      x16, w13, slot_token, offs, (void*)hbuf, nullptr);
  // gemm2: 256x256, split-K=2, M<=18432 x N=1024 x K=4096 -> grid 8*18*4, ORD1
  moe_gemm_kernel<1, 1, 2, 4096, 4, 18, 1024><<<576, 512, 0, stream>>>(
      hbuf, w2h, slot_token, offs, (void*)ybuf, (void*)ybuf2);
  combine_kernel<<<NTOK, 256, 0, stream>>>(ybuf, ybuf2, slot_of, tok_g, out);
}